// Round 1
// baseline (1747.855 us; speedup 1.0000x reference)
//
#include <hip/hip_runtime.h>
#include <hip/hip_bf16.h>

#define B_   32
#define NTOK 3136
#define M_TOT (B_*NTOK)   // 100352

// ---------------------------------------------------------------------------
// LayerNorm over last dim + per-wave column partial sums (for stats).
// One wave per 49 rows (3136 = 64 waves * 49 rows per batch).
// part layout: [b][w][DIN], w < 64 — summed deterministically later.
// ---------------------------------------------------------------------------
template<int DIN>
__global__ __launch_bounds__(256)
void ln_colsum_k(const float* __restrict__ in, const float* __restrict__ gma,
                 const float* __restrict__ bta, float* __restrict__ out,
                 float* __restrict__ part)
{
  constexpr int T = (DIN + 63) / 64;
  const int wid  = (blockIdx.x * 256 + threadIdx.x) >> 6;   // 0..2047
  const int lane = threadIdx.x & 63;
  const int b = wid >> 6;
  const int w = wid & 63;

  float gv[T], bv[T], acc[T];
#pragma unroll
  for (int t = 0; t < T; ++t) {
    int c = lane + 64 * t;
    gv[t] = (c < DIN) ? gma[c] : 0.f;
    bv[t] = (c < DIN) ? bta[c] : 0.f;
    acc[t] = 0.f;
  }

  const size_t rbase = ((size_t)b * NTOK + (size_t)w * 49) * DIN;
  const float* ip = in + rbase;
  float* op = out + rbase;

  for (int j = 0; j < 49; ++j) {
    float v[T];
    float s = 0.f, sq = 0.f;
#pragma unroll
    for (int t = 0; t < T; ++t) {
      int c = lane + 64 * t;
      float xv = (c < DIN) ? ip[(size_t)j * DIN + c] : 0.f;
      v[t] = xv; s += xv; sq += xv * xv;
    }
#pragma unroll
    for (int off = 1; off < 64; off <<= 1) {
      s  += __shfl_xor(s, off);
      sq += __shfl_xor(sq, off);
    }
    float m   = s / (float)DIN;
    float var = sq / (float)DIN - m * m;
    float r   = 1.f / sqrtf(var + 1e-5f);
#pragma unroll
    for (int t = 0; t < T; ++t) {
      int c = lane + 64 * t;
      if (c < DIN) {
        float xn = (v[t] - m) * r * gv[t] + bv[t];
        op[(size_t)j * DIN + c] = xn;
        acc[t] += xn;
      }
    }
  }
#pragma unroll
  for (int t = 0; t < T; ++t) {
    int c = lane + 64 * t;
    if (c < DIN) part[(size_t)(b * 64 + w) * DIN + c] = acc[t];
  }
}

// ---------------------------------------------------------------------------
// Per-batch: reduce partial colsums -> xm; stats = xm@W + bias (linearity of
// mean over N); MLP scores; stable top-k rank (ties -> lower index) -> mask.
// One block per batch.
// ---------------------------------------------------------------------------
template<int DIN, int DOUT>
__global__ __launch_bounds__(256)
void scores_mask_k(const float* __restrict__ part,
                   const float* __restrict__ Wt, const float* __restrict__ bias,
                   const float* __restrict__ W1, const float* __restrict__ b1,
                   const float* __restrict__ W2, const float* __restrict__ b2,
                   float* __restrict__ mask, int k)
{
  __shared__ float xm[DIN];
  __shared__ float st[DOUT];
  __shared__ float h[DOUT / 4];
  __shared__ float sc[DOUT];
  const int b = blockIdx.x, tid = threadIdx.x;

  for (int c = tid; c < DIN; c += 256) {
    float s = 0.f;
    for (int w = 0; w < 64; ++w) s += part[(size_t)(b * 64 + w) * DIN + c];
    xm[c] = s / (float)NTOK;
  }
  __syncthreads();
  for (int c = tid; c < DOUT; c += 256) {
    float s = bias[c];
#pragma unroll 4
    for (int kk = 0; kk < DIN; ++kk) s = fmaf(xm[kk], Wt[(size_t)kk * DOUT + c], s);
    st[c] = s;
  }
  __syncthreads();
  for (int j = tid; j < DOUT / 4; j += 256) {
    float s = b1[j];
#pragma unroll 4
    for (int c = 0; c < DOUT; ++c) s = fmaf(st[c], W1[(size_t)c * (DOUT / 4) + j], s);
    h[j] = fmaxf(s, 0.f);
  }
  __syncthreads();
  for (int c = tid; c < DOUT; c += 256) {
    float s = b2[c];
#pragma unroll 4
    for (int j = 0; j < DOUT / 4; ++j) s = fmaf(h[j], W2[(size_t)j * DOUT + c], s);
    sc[c] = s;
  }
  __syncthreads();
  for (int c = tid; c < DOUT; c += 256) {
    float v = sc[c];
    int rank = 0;
#pragma unroll 4
    for (int j = 0; j < DOUT; ++j) {
      float u = sc[j];
      rank += (u > v) || (u == v && j < c);
    }
    mask[(size_t)b * DOUT + c] = (rank < k) ? 1.f : 0.f;
  }
}

// ---------------------------------------------------------------------------
// fp32 register-tiled GEMM: C[m,n] = (sum_k A[m,k]*W[k,n] + bias[n]) * mask[b,n]
// BM=128, BN=64, BK=32, 256 threads, TM=8 x TN=4 per thread.
// A staged transposed into LDS (As[k][m], padded stride for b128 alignment).
// ---------------------------------------------------------------------------
__global__ __launch_bounds__(256)
void gemm_mask_k(const float* __restrict__ A, const float* __restrict__ Wt,
                 const float* __restrict__ bias, const float* __restrict__ mask,
                 float* __restrict__ C, int K, int N)
{
  constexpr int BM = 128, BN = 64, BK = 32, LDA = BM + 4;
  __shared__ float As[BK][LDA];
  __shared__ float Bs[BK][BN];

  const int tid = threadIdx.x;
  const int tx = tid & 15, ty = tid >> 4;
  const size_t row0 = (size_t)blockIdx.x * BM;
  const int n0b = blockIdx.y * BN;

  const int arow = tid >> 3;          // 0..31
  const int akc  = (tid & 7) << 2;    // 0..28
  const int bk   = tid >> 4;          // 0..15
  const int bn   = (tid & 15) << 2;   // 0..60
  const int nB   = n0b + bn;

  float acc[8][4];
#pragma unroll
  for (int i = 0; i < 8; ++i)
#pragma unroll
    for (int j = 0; j < 4; ++j) acc[i][j] = 0.f;

  const float* aP = A + (row0 + arow) * (size_t)K + akc;
  const float* bP = Wt + (size_t)bk * N + nB;

  for (int k0 = 0; k0 < K; k0 += BK) {
#pragma unroll
    for (int i = 0; i < 4; ++i) {
      float4 a = *(const float4*)(aP + (size_t)(i * 32) * K);
      As[akc + 0][arow + i * 32] = a.x;
      As[akc + 1][arow + i * 32] = a.y;
      As[akc + 2][arow + i * 32] = a.z;
      As[akc + 3][arow + i * 32] = a.w;
    }
#pragma unroll
    for (int i = 0; i < 2; ++i) {
      float4 v = make_float4(0.f, 0.f, 0.f, 0.f);
      if (nB < N) v = *(const float4*)(bP + (size_t)(i * 16) * N);
      *(float4*)&Bs[bk + i * 16][bn] = v;
    }
    __syncthreads();
#pragma unroll 8
    for (int k = 0; k < BK; ++k) {
      float af[8], bf[4];
      *(float4*)&af[0] = *(const float4*)&As[k][ty * 8];
      *(float4*)&af[4] = *(const float4*)&As[k][ty * 8 + 4];
      *(float4*)&bf[0] = *(const float4*)&Bs[k][tx * 4];
#pragma unroll
      for (int i = 0; i < 8; ++i)
#pragma unroll
        for (int j = 0; j < 4; ++j)
          acc[i][j] = fmaf(af[i], bf[j], acc[i][j]);
    }
    __syncthreads();
    aP += BK;
    bP += (size_t)BK * N;
  }

  const int n = n0b + tx * 4;
  if (n < N) {
    float4 bv = *(const float4*)(bias + n);
#pragma unroll
    for (int i = 0; i < 8; ++i) {
      size_t m = row0 + (size_t)ty * 8 + i;
      int bb = (int)(m / NTOK);
      float4 mk = *(const float4*)(mask + (size_t)bb * N + n);
      float4 o;
      o.x = (acc[i][0] + bv.x) * mk.x;
      o.y = (acc[i][1] + bv.y) * mk.y;
      o.z = (acc[i][2] + bv.z) * mk.z;
      o.w = (acc[i][3] + bv.w) * mk.w;
      *(float4*)(C + m * N + n) = o;
    }
  }
}

// ---------------------------------------------------------------------------
extern "C" void kernel_launch(void* const* d_in, const int* in_sizes, int n_in,
                              void* d_out, int out_size, void* d_ws, size_t ws_size,
                              hipStream_t stream)
{
  (void)in_sizes; (void)n_in; (void)out_size; (void)ws_size;
  const float* x = (const float*)d_in[0];
  const float *sg[4], *sb[4], *sW[4], *sbias[4], *pW1[4], *pb1[4], *pW2[4], *pb2[4];
  for (int s = 0; s < 4; ++s) {
    int base = 1 + s * 8;
    sg[s]    = (const float*)d_in[base + 0];
    sb[s]    = (const float*)d_in[base + 1];
    sW[s]    = (const float*)d_in[base + 2];
    sbias[s] = (const float*)d_in[base + 3];
    pW1[s]   = (const float*)d_in[base + 4];
    pb1[s]   = (const float*)d_in[base + 5];
    pW2[s]   = (const float*)d_in[base + 6];
    pb2[s]   = (const float*)d_in[base + 7];
  }

  // workspace: xt (100352*384) + part (32*64*384) + mask (32*768)  ~= 157.4 MB
  float* ws   = (float*)d_ws;
  float* xt   = ws;
  float* part = ws + 38535168;
  float* mk   = part + 786432;

  // intermediates z1..z3 aliased into d_out (dead before GEMM-4 overwrites):
  float* out = (float*)d_out;
  float* z3 = out;              // 100352*384
  float* z2 = out + 38535168;   // 100352*192
  float* z1 = out + 57802752;   // 100352*96  (end 67,436,544 < 77,070,336)

  // ---- stage 1: 96 -> 96, k = int(96*0.9) = 86
  ln_colsum_k<96><<<512, 256, 0, stream>>>(x, sg[0], sb[0], xt, part);
  scores_mask_k<96, 96><<<32, 256, 0, stream>>>(part, sW[0], sbias[0],
      pW1[0], pb1[0], pW2[0], pb2[0], mk, 86);
  gemm_mask_k<<<dim3(784, 2), 256, 0, stream>>>(xt, sW[0], sbias[0], mk, z1, 96, 96);

  // ---- stage 2: 96 -> 192, k = int(192*0.7) = 134
  ln_colsum_k<96><<<512, 256, 0, stream>>>(z1, sg[1], sb[1], xt, part);
  scores_mask_k<96, 192><<<32, 256, 0, stream>>>(part, sW[1], sbias[1],
      pW1[1], pb1[1], pW2[1], pb2[1], mk, 134);
  gemm_mask_k<<<dim3(784, 3), 256, 0, stream>>>(xt, sW[1], sbias[1], mk, z2, 96, 192);

  // ---- stage 3: 192 -> 384, k = int(384*0.5) = 192
  ln_colsum_k<192><<<512, 256, 0, stream>>>(z2, sg[2], sb[2], xt, part);
  scores_mask_k<192, 384><<<32, 256, 0, stream>>>(part, sW[2], sbias[2],
      pW1[2], pb1[2], pW2[2], pb2[2], mk, 192);
  gemm_mask_k<<<dim3(784, 6), 256, 0, stream>>>(xt, sW[2], sbias[2], mk, z3, 192, 384);

  // ---- stage 4: 384 -> 768, k = int(768*0.3) = 230
  ln_colsum_k<384><<<512, 256, 0, stream>>>(z3, sg[3], sb[3], xt, part);
  scores_mask_k<384, 768><<<32, 256, 0, stream>>>(part, sW[3], sbias[3],
      pW1[3], pb1[3], pW2[3], pb2[3], mk, 230);
  gemm_mask_k<<<dim3(784, 12), 256, 0, stream>>>(xt, sW[3], sbias[3], mk, out, 384, 768);
}

// Round 2
// 1058.762 us; speedup vs baseline: 1.6508x; 1.6508x over previous
//
#include <hip/hip_runtime.h>
#include <hip/hip_bf16.h>
#include <stdint.h>

#define NTOK 3136
#define MTOT 100352

typedef __attribute__((ext_vector_type(8))) short bf16x8;
typedef __attribute__((ext_vector_type(4))) float f32x4;

static __device__ __forceinline__ ushort f2bf(float x) {
  union { float f; uint32_t u; } c; c.f = x;
  uint32_t r = (c.u + 0x7FFFu + ((c.u >> 16) & 1u)) >> 16;   // RNE
  return (ushort)r;
}
static __device__ __forceinline__ float bf2f(ushort h) {
  union { uint32_t u; float f; } c; c.u = ((uint32_t)h) << 16;
  return c.f;
}

// ---------------------------------------------------------------------------
// LayerNorm + fp32 column partial sums. Writes bf16 hi (and lo if WLO) for
// the MFMA GEMM; colsums stay fp32-exact so the score chain is unperturbed.
// One wave per 49 rows.
// ---------------------------------------------------------------------------
template<int DIN, bool WLO>
__global__ __launch_bounds__(256)
void ln_colsum_k(const float* __restrict__ in, const float* __restrict__ gma,
                 const float* __restrict__ bta, ushort* __restrict__ oh,
                 ushort* __restrict__ ol, float* __restrict__ part)
{
  constexpr int T = (DIN + 63) / 64;
  const int wid  = (blockIdx.x * 256 + threadIdx.x) >> 6;
  const int lane = threadIdx.x & 63;
  const int b = wid >> 6;
  const int w = wid & 63;

  float gv[T], bv[T], acc[T];
#pragma unroll
  for (int t = 0; t < T; ++t) {
    int c = lane + 64 * t;
    gv[t] = (c < DIN) ? gma[c] : 0.f;
    bv[t] = (c < DIN) ? bta[c] : 0.f;
    acc[t] = 0.f;
  }

  const size_t rbase = ((size_t)b * NTOK + (size_t)w * 49) * DIN;
  const float* ip = in + rbase;
  ushort* oph = oh + rbase;
  ushort* opl = ol + rbase;

  for (int j = 0; j < 49; ++j) {
    float v[T];
    float s = 0.f, sq = 0.f;
#pragma unroll
    for (int t = 0; t < T; ++t) {
      int c = lane + 64 * t;
      float xv = (c < DIN) ? ip[(size_t)j * DIN + c] : 0.f;
      v[t] = xv; s += xv; sq += xv * xv;
    }
#pragma unroll
    for (int off = 1; off < 64; off <<= 1) {
      s  += __shfl_xor(s, off);
      sq += __shfl_xor(sq, off);
    }
    float m   = s / (float)DIN;
    float var = sq / (float)DIN - m * m;
    float r   = 1.f / sqrtf(var + 1e-5f);
#pragma unroll
    for (int t = 0; t < T; ++t) {
      int c = lane + 64 * t;
      if (c < DIN) {
        float xn = (v[t] - m) * r * gv[t] + bv[t];
        ushort h = f2bf(xn);
        oph[(size_t)j * DIN + c] = h;
        if (WLO) opl[(size_t)j * DIN + c] = f2bf(xn - bf2f(h));
        acc[t] += xn;
      }
    }
  }
#pragma unroll
  for (int t = 0; t < T; ++t) {
    int c = lane + 64 * t;
    if (c < DIN) part[(size_t)(b * 64 + w) * DIN + c] = acc[t];
  }
}

// ---------------------------------------------------------------------------
// Per-batch scores + stable top-k rank -> mask (fp32 exact). Unchanged.
// ---------------------------------------------------------------------------
template<int DIN, int DOUT>
__global__ __launch_bounds__(256)
void scores_mask_k(const float* __restrict__ part,
                   const float* __restrict__ Wt, const float* __restrict__ bias,
                   const float* __restrict__ W1, const float* __restrict__ b1,
                   const float* __restrict__ W2, const float* __restrict__ b2,
                   float* __restrict__ mask, int k)
{
  __shared__ float xm[DIN];
  __shared__ float st[DOUT];
  __shared__ float h[DOUT / 4];
  __shared__ float sc[DOUT];
  const int b = blockIdx.x, tid = threadIdx.x;

  for (int c = tid; c < DIN; c += 256) {
    float s = 0.f;
    for (int w = 0; w < 64; ++w) s += part[(size_t)(b * 64 + w) * DIN + c];
    xm[c] = s / (float)NTOK;
  }
  __syncthreads();
  for (int c = tid; c < DOUT; c += 256) {
    float s = bias[c];
#pragma unroll 4
    for (int kk = 0; kk < DIN; ++kk) s = fmaf(xm[kk], Wt[(size_t)kk * DOUT + c], s);
    st[c] = s;
  }
  __syncthreads();
  for (int j = tid; j < DOUT / 4; j += 256) {
    float s = b1[j];
#pragma unroll 4
    for (int c = 0; c < DOUT; ++c) s = fmaf(st[c], W1[(size_t)c * (DOUT / 4) + j], s);
    h[j] = fmaxf(s, 0.f);
  }
  __syncthreads();
  for (int c = tid; c < DOUT; c += 256) {
    float s = b2[c];
#pragma unroll 4
    for (int j = 0; j < DOUT / 4; ++j) s = fmaf(h[j], W2[(size_t)j * DOUT + c], s);
    sc[c] = s;
  }
  __syncthreads();
  for (int c = tid; c < DOUT; c += 256) {
    float v = sc[c];
    int rank = 0;
#pragma unroll 4
    for (int j = 0; j < DOUT; ++j) {
      float u = sc[j];
      rank += (u > v) || (u == v && j < c);
    }
    mask[(size_t)b * DOUT + c] = (rank < k) ? 1.f : 0.f;
  }
}

// ---------------------------------------------------------------------------
// W [K][N] fp32 -> Wt hi/lo bf16 [Npad][K] (transposed, zero-padded rows).
// ---------------------------------------------------------------------------
__global__ __launch_bounds__(256)
void convW_k(const float* __restrict__ W, ushort* __restrict__ hi,
             ushort* __restrict__ lo, int Kd, int N, int Npad)
{
  int idx = blockIdx.x * 256 + threadIdx.x;
  if (idx >= Npad * Kd) return;
  int n = idx / Kd, kk = idx - n * Kd;
  float v = (n < N) ? W[(size_t)kk * N + n] : 0.f;
  ushort h = f2bf(v);
  hi[idx] = h;
  lo[idx] = f2bf(v - bf2f(h));
}

// ---------------------------------------------------------------------------
// MFMA GEMM: C[m,n] = (sum_seg sum_k Aseg[m,k]*Bseg[n,k] + bias[n]) * mask[b,n]
// 128x128 tile, BK=32, 4 waves (64x64 each, 4x4 16x16x32 frags).
// Linear LDS [128 rows][4 slots of 16B]; source-pre-swizzled slot^=(row>>1)&3
// so stride-64B ds_read_b128 frag reads are bank-conflict-free.
// Double-buffered global_load_lds(16B); __syncthreads drains vmcnt.
// ---------------------------------------------------------------------------
#define ASYNC16(GP, LP) __builtin_amdgcn_global_load_lds( \
    (const __attribute__((address_space(1))) void*)(GP),  \
    (__attribute__((address_space(3))) void*)(LP), 16, 0, 0)

template<int K, int NSEG>
__global__ __launch_bounds__(256)
void gemm_mfma_k(const ushort* __restrict__ a0, const ushort* __restrict__ a1,
                 const ushort* __restrict__ a2,
                 const ushort* __restrict__ b0, const ushort* __restrict__ b1,
                 const ushort* __restrict__ b2,
                 const float* __restrict__ bias, const float* __restrict__ msk,
                 float* __restrict__ C, int N)
{
  constexpr int KSTEPS = K / 32;
  constexpr int NT = NSEG * KSTEPS;
  __shared__ __align__(16) ushort ldsA[2][128 * 32];
  __shared__ __align__(16) ushort ldsB[2][128 * 32];

  const int tid  = threadIdx.x;
  const int lane = tid & 63;
  const int wid  = tid >> 6;
  const int wm = wid >> 1, wn = wid & 1;
  const size_t row0 = (size_t)blockIdx.x * 128;
  const int n0 = blockIdx.y * 128;

  const ushort* Aseg[3] = { a0, a1, a2 };
  const ushort* Bseg[3] = { b0, b1, b2 };

  f32x4 acc[4][4];
#pragma unroll
  for (int i = 0; i < 4; ++i)
#pragma unroll
    for (int j = 0; j < 4; ++j) acc[i][j] = { 0.f, 0.f, 0.f, 0.f };

  const int c_row  = tid >> 2;   // +r*64
  const int c_phys = tid & 3;

#define STAGE(BUF, T)                                                          \
  {                                                                            \
    const int seg_ = (T) / KSTEPS;                                             \
    const int k0_  = ((T) % KSTEPS) * 32;                                      \
    const ushort* ap_ = Aseg[seg_];                                            \
    const ushort* bp_ = Bseg[seg_];                                            \
    _Pragma("unroll")                                                          \
    for (int r_ = 0; r_ < 2; ++r_) {                                           \
      int row_  = c_row + r_ * 64;                                             \
      int slot_ = c_phys ^ ((row_ >> 1) & 3);                                  \
      ASYNC16(ap_ + (row0 + row_) * (size_t)K + (k0_ + slot_ * 8),             \
              &ldsA[BUF][(row_ * 4 + c_phys) * 8]);                            \
      ASYNC16(bp_ + (size_t)(n0 + row_) * K + (k0_ + slot_ * 8),               \
              &ldsB[BUF][(row_ * 4 + c_phys) * 8]);                            \
    }                                                                          \
  }

  STAGE(0, 0);
#pragma unroll
  for (int t = 0; t < NT; ++t) {
    __syncthreads();
    if (t + 1 < NT) STAGE((t + 1) & 1, t + 1);
    const int buf = t & 1;
    const int slot = lane >> 4;
    const int r16  = lane & 15;
    bf16x8 af[4], bfr[4];
#pragma unroll
    for (int mi = 0; mi < 4; ++mi) {
      int r = wm * 64 + mi * 16 + r16;
      af[mi] = *(const bf16x8*)&ldsA[buf][(r * 4 + (slot ^ ((r >> 1) & 3))) * 8];
    }
#pragma unroll
    for (int ni = 0; ni < 4; ++ni) {
      int r = wn * 64 + ni * 16 + r16;
      bfr[ni] = *(const bf16x8*)&ldsB[buf][(r * 4 + (slot ^ ((r >> 1) & 3))) * 8];
    }
#pragma unroll
    for (int mi = 0; mi < 4; ++mi)
#pragma unroll
      for (int ni = 0; ni < 4; ++ni)
        acc[mi][ni] = __builtin_amdgcn_mfma_f32_16x16x32_bf16(af[mi], bfr[ni],
                                                              acc[mi][ni], 0, 0, 0);
  }

#pragma unroll
  for (int mi = 0; mi < 4; ++mi) {
#pragma unroll
    for (int ni = 0; ni < 4; ++ni) {
      int n = n0 + wn * 64 + ni * 16 + (lane & 15);
      if (n < N) {
        float bv = bias[n];
#pragma unroll
        for (int q = 0; q < 4; ++q) {
          size_t m = row0 + (size_t)(wm * 64 + mi * 16 + (lane >> 4) * 4 + q);
          uint32_t b = (uint32_t)(m / NTOK);
          C[m * (size_t)N + n] = (acc[mi][ni][q] + bv) * msk[(size_t)b * N + n];
        }
      }
    }
  }
}

// ---------------------------------------------------------------------------
extern "C" void kernel_launch(void* const* d_in, const int* in_sizes, int n_in,
                              void* d_out, int out_size, void* d_ws, size_t ws_size,
                              hipStream_t stream)
{
  (void)in_sizes; (void)n_in; (void)out_size; (void)ws_size;
  const float* x = (const float*)d_in[0];
  const float *sg[4], *sb[4], *sW[4], *sbias[4], *pW1[4], *pb1[4], *pW2[4], *pb2[4];
  for (int s = 0; s < 4; ++s) {
    int base = 1 + s * 8;
    sg[s]    = (const float*)d_in[base + 0];
    sb[s]    = (const float*)d_in[base + 1];
    sW[s]    = (const float*)d_in[base + 2];
    sbias[s] = (const float*)d_in[base + 3];
    pW1[s]   = (const float*)d_in[base + 4];
    pb1[s]   = (const float*)d_in[base + 5];
    pW2[s]   = (const float*)d_in[base + 6];
    pb2[s]   = (const float*)d_in[base + 7];
  }

  // workspace layout (bytes):
  char* ws = (char*)d_ws;
  ushort* a_hi = (ushort*)(ws);                 // 77,070,336 B  (M*384 bf16)
  ushort* a_lo = (ushort*)(ws + 77070336);      // 38,535,168 B  (M*192 bf16)
  float*  part = (float*) (ws + 115605504);     //  3,145,728 B
  float*  mk   = (float*) (ws + 118751232);     //     98,304 B
  ushort* w_hi = (ushort*)(ws + 118849536);     //    589,824 B  (768*384 bf16)
  ushort* w_lo = (ushort*)(ws + 119439360);     //    589,824 B  -> end 120,029,184

  // z1..z3 aliased into d_out (all dead before stage-4 GEMM overwrites):
  float* out = (float*)d_out;
  float* z3 = out;              // M*384
  float* z2 = out + 38535168;   // M*192
  float* z1 = out + 57802752;   // M*96

  // ---- stage 1: K=96 -> N=96 (Npad=128), k = 86
  ln_colsum_k<96, true><<<512, 256, 0, stream>>>(x, sg[0], sb[0], a_hi, a_lo, part);
  scores_mask_k<96, 96><<<32, 256, 0, stream>>>(part, sW[0], sbias[0],
      pW1[0], pb1[0], pW2[0], pb2[0], mk, 86);
  convW_k<<<(128 * 96 + 255) / 256, 256, 0, stream>>>(sW[0], w_hi, w_lo, 96, 96, 128);
  gemm_mfma_k<96, 3><<<dim3(784, 1), 256, 0, stream>>>(
      a_hi, a_hi, a_lo, w_hi, w_lo, w_hi, sbias[0], mk, z1, 96);

  // ---- stage 2: K=96 -> N=192 (Npad=256), k = 134
  ln_colsum_k<96, true><<<512, 256, 0, stream>>>(z1, sg[1], sb[1], a_hi, a_lo, part);
  scores_mask_k<96, 192><<<32, 256, 0, stream>>>(part, sW[1], sbias[1],
      pW1[1], pb1[1], pW2[1], pb2[1], mk, 134);
  convW_k<<<(256 * 96 + 255) / 256, 256, 0, stream>>>(sW[1], w_hi, w_lo, 96, 192, 256);
  gemm_mfma_k<96, 3><<<dim3(784, 2), 256, 0, stream>>>(
      a_hi, a_hi, a_lo, w_hi, w_lo, w_hi, sbias[1], mk, z2, 192);

  // ---- stage 3: K=192 -> N=384, k = 192
  ln_colsum_k<192, true><<<512, 256, 0, stream>>>(z2, sg[2], sb[2], a_hi, a_lo, part);
  scores_mask_k<192, 384><<<32, 256, 0, stream>>>(part, sW[2], sbias[2],
      pW1[2], pb1[2], pW2[2], pb2[2], mk, 192);
  convW_k<<<(384 * 192 + 255) / 256, 256, 0, stream>>>(sW[2], w_hi, w_lo, 192, 384, 384);
  gemm_mfma_k<192, 3><<<dim3(784, 3), 256, 0, stream>>>(
      a_hi, a_hi, a_lo, w_hi, w_lo, w_hi, sbias[2], mk, z3, 384);

  // ---- stage 4: K=384 -> N=768, k = 230 (plain bf16; output-tolerance path)
  ln_colsum_k<384, false><<<512, 256, 0, stream>>>(z3, sg[3], sb[3], a_hi, a_lo, part);
  scores_mask_k<384, 768><<<32, 256, 0, stream>>>(part, sW[3], sbias[3],
      pW1[3], pb1[3], pW2[3], pb2[3], mk, 230);
  convW_k<<<(768 * 384 + 255) / 256, 256, 0, stream>>>(sW[3], w_hi, w_lo, 384, 768, 768);
  gemm_mfma_k<384, 1><<<dim3(784, 6), 256, 0, stream>>>(
      a_hi, a_hi, a_hi, w_hi, w_hi, w_hi, sbias[3], mk, out, 768);
}

// Round 3
// 851.267 us; speedup vs baseline: 2.0532x; 1.2437x over previous
//
#include <hip/hip_runtime.h>
#include <hip/hip_bf16.h>
#include <stdint.h>

#define NTOK 3136
#define MTOT 100352

typedef __attribute__((ext_vector_type(8))) short bf16x8;
typedef __attribute__((ext_vector_type(4))) float f32x4;

static __device__ __forceinline__ ushort f2bf(float x) {
  union { float f; uint32_t u; } c; c.f = x;
  uint32_t r = (c.u + 0x7FFFu + ((c.u >> 16) & 1u)) >> 16;   // RNE
  return (ushort)r;
}
static __device__ __forceinline__ float bf2f(ushort h) {
  union { uint32_t u; float f; } c; c.u = ((uint32_t)h) << 16;
  return c.f;
}

// ---------------------------------------------------------------------------
// LayerNorm + fp32 column partial sums. Writes bf16 hi (and lo if WLO).
// One wave per 49 rows.
// ---------------------------------------------------------------------------
template<int DIN, bool WLO>
__global__ __launch_bounds__(256)
void ln_colsum_k(const float* __restrict__ in, const float* __restrict__ gma,
                 const float* __restrict__ bta, ushort* __restrict__ oh,
                 ushort* __restrict__ ol, float* __restrict__ part)
{
  constexpr int T = (DIN + 63) / 64;
  const int wid  = (blockIdx.x * 256 + threadIdx.x) >> 6;
  const int lane = threadIdx.x & 63;
  const int b = wid >> 6;
  const int w = wid & 63;

  float gv[T], bv[T], acc[T];
#pragma unroll
  for (int t = 0; t < T; ++t) {
    int c = lane + 64 * t;
    gv[t] = (c < DIN) ? gma[c] : 0.f;
    bv[t] = (c < DIN) ? bta[c] : 0.f;
    acc[t] = 0.f;
  }

  const size_t rbase = ((size_t)b * NTOK + (size_t)w * 49) * DIN;
  const float* ip = in + rbase;
  ushort* oph = oh + rbase;
  ushort* opl = ol + rbase;

  for (int j = 0; j < 49; ++j) {
    float v[T];
    float s = 0.f, sq = 0.f;
#pragma unroll
    for (int t = 0; t < T; ++t) {
      int c = lane + 64 * t;
      float xv = (c < DIN) ? ip[(size_t)j * DIN + c] : 0.f;
      v[t] = xv; s += xv; sq += xv * xv;
    }
#pragma unroll
    for (int off = 1; off < 64; off <<= 1) {
      s  += __shfl_xor(s, off);
      sq += __shfl_xor(sq, off);
    }
    float m   = s / (float)DIN;
    float var = sq / (float)DIN - m * m;
    float r   = 1.f / sqrtf(var + 1e-5f);
#pragma unroll
    for (int t = 0; t < T; ++t) {
      int c = lane + 64 * t;
      if (c < DIN) {
        float xn = (v[t] - m) * r * gv[t] + bv[t];
        ushort hh = f2bf(xn);
        oph[(size_t)j * DIN + c] = hh;
        if (WLO) opl[(size_t)j * DIN + c] = f2bf(xn - bf2f(hh));
        acc[t] += xn;
      }
    }
  }
#pragma unroll
  for (int t = 0; t < T; ++t) {
    int c = lane + 64 * t;
    if (c < DIN) part[(size_t)(b * 64 + w) * DIN + c] = acc[t];
  }
}

// ---------------------------------------------------------------------------
// Scores + stable top-k -> mask. 1024 threads/block, one block per batch.
// Every matvec splits its reduction dim over 4 thread-slices (coalesced over
// the output dim), partials combined in fixed order (deterministic fp32).
// ---------------------------------------------------------------------------
template<int DIN, int DOUT>
__global__ __launch_bounds__(1024)
void scores_mask_k(const float* __restrict__ part,
                   const float* __restrict__ Wt, const float* __restrict__ bias,
                   const float* __restrict__ W1, const float* __restrict__ b1,
                   const float* __restrict__ W2, const float* __restrict__ b2,
                   float* __restrict__ mask, int k)
{
  constexpr int DH = DOUT / 4;
  constexpr int NC = (DOUT + 255) / 256;   // cols per thread (<=3)
  __shared__ float xm[DIN];
  __shared__ float red[4][DOUT];
  __shared__ float st[DOUT];
  __shared__ float h[DH];
  __shared__ float sc[DOUT];
  const int b = blockIdx.x, tid = threadIdx.x;
  const int slice = tid >> 8, ct = tid & 255;

  // phase 0: reduce part -> xm (2 w-groups of 32)
  {
    int g = tid >> 9, c = tid & 511;
    if (c < DIN) {
      float s = 0.f;
      const float* p = part + ((size_t)b * 64 + g * 32) * DIN + c;
#pragma unroll 8
      for (int w = 0; w < 32; ++w) s += p[(size_t)w * DIN];
      red[g][c] = s;
    }
  }
  __syncthreads();
  if (tid < DIN) xm[tid] = (red[0][tid] + red[1][tid]) * (1.f / (float)NTOK);
  __syncthreads();

  // phase 1: st = xm @ W + bias   (reduce DIN over 4 slices)
  {
    constexpr int KS = DIN / 4;
    const float* wp = Wt + (size_t)slice * KS * DOUT;
    float s[NC];
#pragma unroll
    for (int i = 0; i < NC; ++i) s[i] = 0.f;
#pragma unroll
    for (int kk = 0; kk < KS; ++kk) {
      float xv = xm[slice * KS + kk];
#pragma unroll
      for (int i = 0; i < NC; ++i) {
        int c = ct + i * 256;
        if (c < DOUT) s[i] = fmaf(xv, wp[(size_t)kk * DOUT + c], s[i]);
      }
    }
#pragma unroll
    for (int i = 0; i < NC; ++i) {
      int c = ct + i * 256;
      if (c < DOUT) red[slice][c] = s[i];
    }
  }
  __syncthreads();
  for (int c = tid; c < DOUT; c += 1024)
    st[c] = red[0][c] + red[1][c] + red[2][c] + red[3][c] + bias[c];
  __syncthreads();

  // phase 2: h = relu(st @ W1 + b1)   (reduce DOUT over 4 slices)
  {
    constexpr int CS = DOUT / 4;
    const float* wp = W1 + (size_t)slice * CS * DH;
    if (ct < DH) {
      float s = 0.f;
#pragma unroll
      for (int cc = 0; cc < CS; ++cc)
        s = fmaf(st[slice * CS + cc], wp[(size_t)cc * DH + ct], s);
      red[slice][ct] = s;
    }
  }
  __syncthreads();
  if (tid < DH)
    h[tid] = fmaxf(red[0][tid] + red[1][tid] + red[2][tid] + red[3][tid] + b1[tid], 0.f);
  __syncthreads();

  // phase 3: sc = h @ W2 + b2   (reduce DH over 4 slices)
  {
    constexpr int JS = DH / 4;
    const float* wp = W2 + (size_t)slice * JS * DOUT;
    float s[NC];
#pragma unroll
    for (int i = 0; i < NC; ++i) s[i] = 0.f;
#pragma unroll
    for (int jj = 0; jj < JS; ++jj) {
      float hv = h[slice * JS + jj];
#pragma unroll
      for (int i = 0; i < NC; ++i) {
        int c = ct + i * 256;
        if (c < DOUT) s[i] = fmaf(hv, wp[(size_t)jj * DOUT + c], s[i]);
      }
    }
#pragma unroll
    for (int i = 0; i < NC; ++i) {
      int c = ct + i * 256;
      if (c < DOUT) red[slice][c] = s[i];
    }
  }
  __syncthreads();
  for (int c = tid; c < DOUT; c += 1024)
    sc[c] = red[0][c] + red[1][c] + red[2][c] + red[3][c] + b2[c];
  __syncthreads();

  // phase 4: stable rank -> mask
  for (int c = tid; c < DOUT; c += 1024) {
    float v = sc[c];
    int rank = 0;
#pragma unroll 8
    for (int j = 0; j < DOUT; ++j) {
      float u = sc[j];
      rank += (u > v) || (u == v && j < c);
    }
    mask[(size_t)b * DOUT + c] = (rank < k) ? 1.f : 0.f;
  }
}

// ---------------------------------------------------------------------------
// All 4 stages' W [K][N] fp32 -> hi/lo bf16 [Npad][K], hoisted to the start.
// ---------------------------------------------------------------------------
__global__ __launch_bounds__(256)
void convW_all_k(const float* __restrict__ W0, const float* __restrict__ W1,
                 const float* __restrict__ W2, const float* __restrict__ W3,
                 ushort* __restrict__ hi, ushort* __restrict__ lo)
{
  const int Kd[4]   = { 96, 96, 192, 384 };
  const int Nd[4]   = { 96, 192, 384, 768 };
  const int off[5]  = { 0, 12288, 36864, 110592, 405504 };
  const float* Wp[4] = { W0, W1, W2, W3 };

  int idx = blockIdx.x * 256 + threadIdx.x;
  if (idx >= 405504) return;
  int s = (idx >= off[1]) + (idx >= off[2]) + (idx >= off[3]);
  int local = idx - off[s];
  int K = Kd[s], N = Nd[s];
  int n = local / K, kk = local - n * K;
  float v = (n < N) ? Wp[s][(size_t)kk * N + n] : 0.f;
  ushort h = f2bf(v);
  hi[idx] = h;
  lo[idx] = f2bf(v - bf2f(h));
}

// ---------------------------------------------------------------------------
// MFMA GEMM (unchanged from round 2): 128x128 tile, BK=32, 4 waves, source-
// pre-swizzled linear LDS + global_load_lds(16B), double-buffered.
// ---------------------------------------------------------------------------
#define ASYNC16(GP, LP) __builtin_amdgcn_global_load_lds( \
    (const __attribute__((address_space(1))) void*)(GP),  \
    (__attribute__((address_space(3))) void*)(LP), 16, 0, 0)

template<int K, int NSEG>
__global__ __launch_bounds__(256)
void gemm_mfma_k(const ushort* __restrict__ a0, const ushort* __restrict__ a1,
                 const ushort* __restrict__ a2,
                 const ushort* __restrict__ b0, const ushort* __restrict__ b1,
                 const ushort* __restrict__ b2,
                 const float* __restrict__ bias, const float* __restrict__ msk,
                 float* __restrict__ C, int N)
{
  constexpr int KSTEPS = K / 32;
  constexpr int NT = NSEG * KSTEPS;
  __shared__ __align__(16) ushort ldsA[2][128 * 32];
  __shared__ __align__(16) ushort ldsB[2][128 * 32];

  const int tid  = threadIdx.x;
  const int lane = tid & 63;
  const int wid  = tid >> 6;
  const int wm = wid >> 1, wn = wid & 1;
  const size_t row0 = (size_t)blockIdx.x * 128;
  const int n0 = blockIdx.y * 128;

  const ushort* Aseg[3] = { a0, a1, a2 };
  const ushort* Bseg[3] = { b0, b1, b2 };

  f32x4 acc[4][4];
#pragma unroll
  for (int i = 0; i < 4; ++i)
#pragma unroll
    for (int j = 0; j < 4; ++j) acc[i][j] = { 0.f, 0.f, 0.f, 0.f };

  const int c_row  = tid >> 2;
  const int c_phys = tid & 3;

#define STAGE(BUF, T)                                                          \
  {                                                                            \
    const int seg_ = (T) / KSTEPS;                                             \
    const int k0_  = ((T) % KSTEPS) * 32;                                      \
    const ushort* ap_ = Aseg[seg_];                                            \
    const ushort* bp_ = Bseg[seg_];                                            \
    _Pragma("unroll")                                                          \
    for (int r_ = 0; r_ < 2; ++r_) {                                           \
      int row_  = c_row + r_ * 64;                                             \
      int slot_ = c_phys ^ ((row_ >> 1) & 3);                                  \
      ASYNC16(ap_ + (row0 + row_) * (size_t)K + (k0_ + slot_ * 8),             \
              &ldsA[BUF][(row_ * 4 + c_phys) * 8]);                            \
      ASYNC16(bp_ + (size_t)(n0 + row_) * K + (k0_ + slot_ * 8),               \
              &ldsB[BUF][(row_ * 4 + c_phys) * 8]);                            \
    }                                                                          \
  }

  STAGE(0, 0);
#pragma unroll
  for (int t = 0; t < NT; ++t) {
    __syncthreads();
    if (t + 1 < NT) STAGE((t + 1) & 1, t + 1);
    const int buf = t & 1;
    const int slot = lane >> 4;
    const int r16  = lane & 15;
    bf16x8 af[4], bfr[4];
#pragma unroll
    for (int mi = 0; mi < 4; ++mi) {
      int r = wm * 64 + mi * 16 + r16;
      af[mi] = *(const bf16x8*)&ldsA[buf][(r * 4 + (slot ^ ((r >> 1) & 3))) * 8];
    }
#pragma unroll
    for (int ni = 0; ni < 4; ++ni) {
      int r = wn * 64 + ni * 16 + r16;
      bfr[ni] = *(const bf16x8*)&ldsB[buf][(r * 4 + (slot ^ ((r >> 1) & 3))) * 8];
    }
#pragma unroll
    for (int mi = 0; mi < 4; ++mi)
#pragma unroll
      for (int ni = 0; ni < 4; ++ni)
        acc[mi][ni] = __builtin_amdgcn_mfma_f32_16x16x32_bf16(af[mi], bfr[ni],
                                                              acc[mi][ni], 0, 0, 0);
  }

#pragma unroll
  for (int mi = 0; mi < 4; ++mi) {
#pragma unroll
    for (int ni = 0; ni < 4; ++ni) {
      int n = n0 + wn * 64 + ni * 16 + (lane & 15);
      if (n < N) {
        float bv = bias[n];
#pragma unroll
        for (int q = 0; q < 4; ++q) {
          size_t m = row0 + (size_t)(wm * 64 + mi * 16 + (lane >> 4) * 4 + q);
          uint32_t b = (uint32_t)(m / NTOK);
          C[m * (size_t)N + n] = (acc[mi][ni][q] + bv) * msk[(size_t)b * N + n];
        }
      }
    }
  }
}

// ---------------------------------------------------------------------------
extern "C" void kernel_launch(void* const* d_in, const int* in_sizes, int n_in,
                              void* d_out, int out_size, void* d_ws, size_t ws_size,
                              hipStream_t stream)
{
  (void)in_sizes; (void)n_in; (void)out_size; (void)ws_size;
  const float* x = (const float*)d_in[0];
  const float *sg[4], *sb[4], *sW[4], *sbias[4], *pW1[4], *pb1[4], *pW2[4], *pb2[4];
  for (int s = 0; s < 4; ++s) {
    int base = 1 + s * 8;
    sg[s]    = (const float*)d_in[base + 0];
    sb[s]    = (const float*)d_in[base + 1];
    sW[s]    = (const float*)d_in[base + 2];
    sbias[s] = (const float*)d_in[base + 3];
    pW1[s]   = (const float*)d_in[base + 4];
    pb1[s]   = (const float*)d_in[base + 5];
    pW2[s]   = (const float*)d_in[base + 6];
    pb2[s]   = (const float*)d_in[base + 7];
  }

  // workspace layout (bytes, all 16-aligned):
  char* ws = (char*)d_ws;
  ushort* a_hi = (ushort*)(ws);                 // 77,070,336  (M*384 bf16)
  ushort* a_lo = (ushort*)(ws + 77070336);      // 38,535,168  (M*192 bf16)
  float*  part = (float*) (ws + 115605504);     //  3,145,728
  float*  mk   = (float*) (ws + 118751232);     //     98,304
  ushort* w_hi = (ushort*)(ws + 118849536);     //    811,008  (405504 bf16)
  ushort* w_lo = (ushort*)(ws + 119660544);     //    811,008  -> end 120,471,552

  // per-stage weight offsets (elements) in w_hi / w_lo:
  const int woff[4] = { 0, 12288, 36864, 110592 };

  // z1..z3 aliased into d_out (all dead before stage-4 GEMM overwrites):
  float* out = (float*)d_out;
  float* z3 = out;              // M*384
  float* z2 = out + 38535168;   // M*192
  float* z1 = out + 57802752;   // M*96

  // ---- hoisted: convert all stage weights to bf16 hi/lo, transposed/padded
  convW_all_k<<<(405504 + 255) / 256, 256, 0, stream>>>(
      sW[0], sW[1], sW[2], sW[3], w_hi, w_lo);

  // ---- stage 1: K=96 -> N=96 (Npad=128), k = 86
  ln_colsum_k<96, true><<<512, 256, 0, stream>>>(x, sg[0], sb[0], a_hi, a_lo, part);
  scores_mask_k<96, 96><<<32, 1024, 0, stream>>>(part, sW[0], sbias[0],
      pW1[0], pb1[0], pW2[0], pb2[0], mk, 86);
  gemm_mfma_k<96, 3><<<dim3(784, 1), 256, 0, stream>>>(
      a_hi, a_hi, a_lo, w_hi + woff[0], w_lo + woff[0], w_hi + woff[0],
      sbias[0], mk, z1, 96);

  // ---- stage 2: K=96 -> N=192 (Npad=256), k = 134
  ln_colsum_k<96, true><<<512, 256, 0, stream>>>(z1, sg[1], sb[1], a_hi, a_lo, part);
  scores_mask_k<96, 192><<<32, 1024, 0, stream>>>(part, sW[1], sbias[1],
      pW1[1], pb1[1], pW2[1], pb2[1], mk, 134);
  gemm_mfma_k<96, 3><<<dim3(784, 2), 256, 0, stream>>>(
      a_hi, a_hi, a_lo, w_hi + woff[1], w_lo + woff[1], w_hi + woff[1],
      sbias[1], mk, z2, 192);

  // ---- stage 3: K=192 -> N=384, k = 192
  ln_colsum_k<192, true><<<512, 256, 0, stream>>>(z2, sg[2], sb[2], a_hi, a_lo, part);
  scores_mask_k<192, 384><<<32, 1024, 0, stream>>>(part, sW[2], sbias[2],
      pW1[2], pb1[2], pW2[2], pb2[2], mk, 192);
  gemm_mfma_k<192, 3><<<dim3(784, 3), 256, 0, stream>>>(
      a_hi, a_hi, a_lo, w_hi + woff[2], w_lo + woff[2], w_hi + woff[2],
      sbias[2], mk, z3, 384);

  // ---- stage 4: K=384 -> N=768, k = 230 (plain bf16; output-tolerance path)
  ln_colsum_k<384, false><<<512, 256, 0, stream>>>(z3, sg[3], sb[3], a_hi, a_hi, part);
  scores_mask_k<384, 768><<<32, 1024, 0, stream>>>(part, sW[3], sbias[3],
      pW1[3], pb1[3], pW2[3], pb2[3], mk, 230);
  gemm_mfma_k<384, 1><<<dim3(784, 6), 256, 0, stream>>>(
      a_hi, a_hi, a_hi, w_hi + woff[3], w_hi + woff[3], w_hi + woff[3],
      sbias[3], mk, out, 768);
}

// Round 4
// 669.201 us; speedup vs baseline: 2.6119x; 1.2721x over previous
//
#include <hip/hip_runtime.h>
#include <hip/hip_bf16.h>
#include <stdint.h>

#define NTOK 3136
#define MTOT 100352

typedef __attribute__((ext_vector_type(8))) short bf16x8;
typedef __attribute__((ext_vector_type(4))) float f32x4;

static __device__ __forceinline__ ushort f2bf(float x) {
  union { float f; uint32_t u; } c; c.f = x;
  uint32_t r = (c.u + 0x7FFFu + ((c.u >> 16) & 1u)) >> 16;   // RNE
  return (ushort)r;
}
static __device__ __forceinline__ float bf2f(ushort h) {
  union { uint32_t u; float f; } c; c.u = ((uint32_t)h) << 16;
  return c.f;
}

// ---------------------------------------------------------------------------
// LayerNorm + fp32 column partial sums. Writes bf16 hi (and lo if WLO).
// part is written TRANSPOSED: part[b][c][w] (w = wave 0..63) so the reducer
// reads contiguous float4s.
// ---------------------------------------------------------------------------
template<int DIN, bool WLO>
__global__ __launch_bounds__(256)
void ln_colsum_k(const float* __restrict__ in, const float* __restrict__ gma,
                 const float* __restrict__ bta, ushort* __restrict__ oh,
                 ushort* __restrict__ ol, float* __restrict__ part)
{
  constexpr int T = (DIN + 63) / 64;
  const int wid  = (blockIdx.x * 256 + threadIdx.x) >> 6;
  const int lane = threadIdx.x & 63;
  const int b = wid >> 6;
  const int w = wid & 63;

  float gv[T], bv[T], acc[T];
#pragma unroll
  for (int t = 0; t < T; ++t) {
    int c = lane + 64 * t;
    gv[t] = (c < DIN) ? gma[c] : 0.f;
    bv[t] = (c < DIN) ? bta[c] : 0.f;
    acc[t] = 0.f;
  }

  const size_t rbase = ((size_t)b * NTOK + (size_t)w * 49) * DIN;
  const float* ip = in + rbase;
  ushort* oph = oh + rbase;
  ushort* opl = ol + rbase;

  for (int j = 0; j < 49; ++j) {
    float v[T];
    float s = 0.f, sq = 0.f;
#pragma unroll
    for (int t = 0; t < T; ++t) {
      int c = lane + 64 * t;
      float xv = (c < DIN) ? ip[(size_t)j * DIN + c] : 0.f;
      v[t] = xv; s += xv; sq += xv * xv;
    }
#pragma unroll
    for (int off = 1; off < 64; off <<= 1) {
      s  += __shfl_xor(s, off);
      sq += __shfl_xor(sq, off);
    }
    float m   = s / (float)DIN;
    float var = sq / (float)DIN - m * m;
    float r   = 1.f / sqrtf(var + 1e-5f);
#pragma unroll
    for (int t = 0; t < T; ++t) {
      int c = lane + 64 * t;
      if (c < DIN) {
        float xn = (v[t] - m) * r * gv[t] + bv[t];
        ushort hh = f2bf(xn);
        oph[(size_t)j * DIN + c] = hh;
        if (WLO) opl[(size_t)j * DIN + c] = f2bf(xn - bf2f(hh));
        acc[t] += xn;
      }
    }
  }
#pragma unroll
  for (int t = 0; t < T; ++t) {
    int c = lane + 64 * t;
    if (c < DIN) part[((size_t)b * DIN + c) * 64 + w] = acc[t];
  }
}

// ---------------------------------------------------------------------------
// st_k: per (batch, col-chunk): xm = mean_tokens (from transposed part),
// st[chunk cols] = xm @ W + bias  -> global. 8 k-slices x float4-cols.
// ---------------------------------------------------------------------------
template<int DIN, int DOUT, int CHUNKS, int BLK>
__global__ __launch_bounds__(BLK)
void st_k(const float* __restrict__ part, const float* __restrict__ Wt,
          const float* __restrict__ bias, float* __restrict__ st_g)
{
  constexpr int C4 = DOUT / 4 / CHUNKS;   // float4 cols per chunk
  constexpr int CW = C4 * 4;
  constexpr int SL = 8;
  constexpr int RPS = DIN / SL;
  static_assert(BLK == C4 * SL, "block size");
  constexpr int CG = BLK / 4;             // col-groups in phase A
  static_assert(DIN % CG == 0, "phase A tiling");

  __shared__ float xm[DIN];
  __shared__ float redA[4][DIN];
  __shared__ float redB[SL][CW];

  const int b = blockIdx.x, ch = blockIdx.y, tid = threadIdx.x;

  // phase A: xm (4 threads per column, 4 independent float4 each)
  {
    const int cg = tid >> 2, wq = tid & 3;
#pragma unroll
    for (int i = 0; i < DIN / CG; ++i) {
      int c = cg + i * CG;
      const float* p = part + ((size_t)b * DIN + c) * 64 + wq * 16;
      f32x4 a0 = *(const f32x4*)(p + 0);
      f32x4 a1 = *(const f32x4*)(p + 4);
      f32x4 a2 = *(const f32x4*)(p + 8);
      f32x4 a3 = *(const f32x4*)(p + 12);
      float s = (((a0[0]+a0[1])+(a0[2]+a0[3])) + ((a1[0]+a1[1])+(a1[2]+a1[3])))
              + (((a2[0]+a2[1])+(a2[2]+a2[3])) + ((a3[0]+a3[1])+(a3[2]+a3[3])));
      redA[wq][c] = s;
    }
  }
  __syncthreads();
  for (int c = tid; c < DIN; c += BLK)
    xm[c] = ((redA[0][c]+redA[1][c]) + (redA[2][c]+redA[3][c])) * (1.f/(float)NTOK);
  __syncthreads();

  // phase B: st chunk = xm @ W + bias
  {
    const int j4 = tid % C4, sl = tid / C4;
    const float* wp = Wt + (size_t)(sl * RPS) * DOUT + ch * CW + j4 * 4;
    f32x4 acc = {0.f, 0.f, 0.f, 0.f};
#pragma unroll
    for (int r = 0; r < RPS; ++r) {
      f32x4 wv = *(const f32x4*)(wp + (size_t)r * DOUT);
      float xv = xm[sl * RPS + r];
      acc[0] = fmaf(xv, wv[0], acc[0]);
      acc[1] = fmaf(xv, wv[1], acc[1]);
      acc[2] = fmaf(xv, wv[2], acc[2]);
      acc[3] = fmaf(xv, wv[3], acc[3]);
    }
    *(f32x4*)&redB[sl][j4 * 4] = acc;
  }
  __syncthreads();
  if (tid < CW) {
    int c = ch * CW + tid;
    float t0 = (redB[0][tid]+redB[1][tid]) + (redB[2][tid]+redB[3][tid]);
    float t1 = (redB[4][tid]+redB[5][tid]) + (redB[6][tid]+redB[7][tid]);
    st_g[(size_t)b * DOUT + c] = bias[c] + t0 + t1;
  }
}

// ---------------------------------------------------------------------------
// hscrank_k: per batch: h = relu(st@W1+b1), sc = h@W2+b2, stable rank -> mask.
// Reduction dims sliced over up-to-64 slices; fixed-order combines.
// ---------------------------------------------------------------------------
template<int DOUT>
__global__ __launch_bounds__(1024)
void hscrank_k(const float* __restrict__ st_g,
               const float* __restrict__ W1, const float* __restrict__ b1,
               const float* __restrict__ W2, const float* __restrict__ b2,
               float* __restrict__ mask, int k)
{
  constexpr int DH  = DOUT / 4;
  constexpr int DH4 = DH / 4;
  constexpr int NSLC = (1024 / DH4 < 64) ? 1024 / DH4 : 64;
  constexpr int RPSC = (DOUT + NSLC - 1) / NSLC;
  constexpr int C4  = DOUT / 4;
  constexpr int NSLD = (1024 / C4 < 64) ? 1024 / C4 : 64;
  constexpr int RPSD = (DH + NSLD - 1) / NSLD;

  __shared__ float st[DOUT];
  __shared__ float h[DH];
  __shared__ float sc[DOUT];
  __shared__ float red[4096];

  const int b = blockIdx.x, tid = threadIdx.x;

  for (int c = tid; c < DOUT; c += 1024) st[c] = st_g[(size_t)b * DOUT + c];
  __syncthreads();

  // phase C: h = relu(st @ W1 + b1), reduce DOUT over NSLC slices
  {
    const int j4 = tid % DH4, sl = tid / DH4;
    if (sl < NSLC) {
      f32x4 acc = {0.f, 0.f, 0.f, 0.f};
#pragma unroll
      for (int rr = 0; rr < RPSC; ++rr) {
        int r = sl * RPSC + rr;
        if (r < DOUT) {
          f32x4 wv = *(const f32x4*)(W1 + (size_t)r * DH + j4 * 4);
          float sv = st[r];
          acc[0] = fmaf(sv, wv[0], acc[0]);
          acc[1] = fmaf(sv, wv[1], acc[1]);
          acc[2] = fmaf(sv, wv[2], acc[2]);
          acc[3] = fmaf(sv, wv[3], acc[3]);
        }
      }
      *(f32x4*)&red[(size_t)sl * DH + j4 * 4] = acc;
    }
  }
  __syncthreads();
  if (tid < DH) {
    float a = 0.f;
#pragma unroll 4
    for (int sl = 0; sl < NSLC; ++sl) a += red[(size_t)sl * DH + tid];
    h[tid] = fmaxf(b1[tid] + a, 0.f);
  }
  __syncthreads();

  // phase D: sc = h @ W2 + b2, reduce DH over NSLD slices
  {
    const int c4 = tid % C4, sl = tid / C4;
    if (sl < NSLD) {
      f32x4 acc = {0.f, 0.f, 0.f, 0.f};
#pragma unroll
      for (int rr = 0; rr < RPSD; ++rr) {
        int r = sl * RPSD + rr;
        if (r < DH) {
          f32x4 wv = *(const f32x4*)(W2 + (size_t)r * DOUT + c4 * 4);
          float hv = h[r];
          acc[0] = fmaf(hv, wv[0], acc[0]);
          acc[1] = fmaf(hv, wv[1], acc[1]);
          acc[2] = fmaf(hv, wv[2], acc[2]);
          acc[3] = fmaf(hv, wv[3], acc[3]);
        }
      }
      *(f32x4*)&red[(size_t)sl * DOUT + c4 * 4] = acc;
    }
  }
  __syncthreads();
  for (int c = tid; c < DOUT; c += 1024) {
    float a = 0.f;
#pragma unroll 4
    for (int sl = 0; sl < NSLD; ++sl) a += red[(size_t)sl * DOUT + c];
    sc[c] = b2[c] + a;
  }
  __syncthreads();

  // phase E: stable rank -> mask
  for (int c = tid; c < DOUT; c += 1024) {
    float v = sc[c];
    int rank = 0;
#pragma unroll 8
    for (int j = 0; j < DOUT; ++j) {
      float u = sc[j];
      rank += (u > v) || (u == v && j < c);
    }
    mask[(size_t)b * DOUT + c] = (rank < k) ? 1.f : 0.f;
  }
}

// ---------------------------------------------------------------------------
// All 4 stages' W [K][N] fp32 -> hi/lo bf16 [Npad][K], hoisted to the start.
// ---------------------------------------------------------------------------
__global__ __launch_bounds__(256)
void convW_all_k(const float* __restrict__ W0, const float* __restrict__ W1,
                 const float* __restrict__ W2, const float* __restrict__ W3,
                 ushort* __restrict__ hi, ushort* __restrict__ lo)
{
  const int Kd[4]   = { 96, 96, 192, 384 };
  const int Nd[4]   = { 96, 192, 384, 768 };
  const int off[5]  = { 0, 12288, 36864, 110592, 405504 };
  const float* Wp[4] = { W0, W1, W2, W3 };

  int idx = blockIdx.x * 256 + threadIdx.x;
  if (idx >= 405504) return;
  int s = (idx >= off[1]) + (idx >= off[2]) + (idx >= off[3]);
  int local = idx - off[s];
  int K = Kd[s], N = Nd[s];
  int n = local / K, kk = local - n * K;
  float v = (n < N) ? Wp[s][(size_t)kk * N + n] : 0.f;
  ushort h = f2bf(v);
  hi[idx] = h;
  lo[idx] = f2bf(v - bf2f(h));
}

// ---------------------------------------------------------------------------
// MFMA GEMM (unchanged): 128x128 tile, BK=32, 4 waves, source-pre-swizzled
// linear LDS + global_load_lds(16B), double-buffered.
// ---------------------------------------------------------------------------
#define ASYNC16(GP, LP) __builtin_amdgcn_global_load_lds( \
    (const __attribute__((address_space(1))) void*)(GP),  \
    (__attribute__((address_space(3))) void*)(LP), 16, 0, 0)

template<int K, int NSEG>
__global__ __launch_bounds__(256)
void gemm_mfma_k(const ushort* __restrict__ a0, const ushort* __restrict__ a1,
                 const ushort* __restrict__ a2,
                 const ushort* __restrict__ b0, const ushort* __restrict__ b1,
                 const ushort* __restrict__ b2,
                 const float* __restrict__ bias, const float* __restrict__ msk,
                 float* __restrict__ C, int N)
{
  constexpr int KSTEPS = K / 32;
  constexpr int NT = NSEG * KSTEPS;
  __shared__ __align__(16) ushort ldsA[2][128 * 32];
  __shared__ __align__(16) ushort ldsB[2][128 * 32];

  const int tid  = threadIdx.x;
  const int lane = tid & 63;
  const int wid  = tid >> 6;
  const int wm = wid >> 1, wn = wid & 1;
  const size_t row0 = (size_t)blockIdx.x * 128;
  const int n0 = blockIdx.y * 128;

  const ushort* Aseg[3] = { a0, a1, a2 };
  const ushort* Bseg[3] = { b0, b1, b2 };

  f32x4 acc[4][4];
#pragma unroll
  for (int i = 0; i < 4; ++i)
#pragma unroll
    for (int j = 0; j < 4; ++j) acc[i][j] = { 0.f, 0.f, 0.f, 0.f };

  const int c_row  = tid >> 2;
  const int c_phys = tid & 3;

#define STAGE(BUF, T)                                                          \
  {                                                                            \
    const int seg_ = (T) / KSTEPS;                                             \
    const int k0_  = ((T) % KSTEPS) * 32;                                      \
    const ushort* ap_ = Aseg[seg_];                                            \
    const ushort* bp_ = Bseg[seg_];                                            \
    _Pragma("unroll")                                                          \
    for (int r_ = 0; r_ < 2; ++r_) {                                           \
      int row_  = c_row + r_ * 64;                                             \
      int slot_ = c_phys ^ ((row_ >> 1) & 3);                                  \
      ASYNC16(ap_ + (row0 + row_) * (size_t)K + (k0_ + slot_ * 8),             \
              &ldsA[BUF][(row_ * 4 + c_phys) * 8]);                            \
      ASYNC16(bp_ + (size_t)(n0 + row_) * K + (k0_ + slot_ * 8),               \
              &ldsB[BUF][(row_ * 4 + c_phys) * 8]);                            \
    }                                                                          \
  }

  STAGE(0, 0);
#pragma unroll
  for (int t = 0; t < NT; ++t) {
    __syncthreads();
    if (t + 1 < NT) STAGE((t + 1) & 1, t + 1);
    const int buf = t & 1;
    const int slot = lane >> 4;
    const int r16  = lane & 15;
    bf16x8 af[4], bfr[4];
#pragma unroll
    for (int mi = 0; mi < 4; ++mi) {
      int r = wm * 64 + mi * 16 + r16;
      af[mi] = *(const bf16x8*)&ldsA[buf][(r * 4 + (slot ^ ((r >> 1) & 3))) * 8];
    }
#pragma unroll
    for (int ni = 0; ni < 4; ++ni) {
      int r = wn * 64 + ni * 16 + r16;
      bfr[ni] = *(const bf16x8*)&ldsB[buf][(r * 4 + (slot ^ ((r >> 1) & 3))) * 8];
    }
#pragma unroll
    for (int mi = 0; mi < 4; ++mi)
#pragma unroll
      for (int ni = 0; ni < 4; ++ni)
        acc[mi][ni] = __builtin_amdgcn_mfma_f32_16x16x32_bf16(af[mi], bfr[ni],
                                                              acc[mi][ni], 0, 0, 0);
  }

#pragma unroll
  for (int mi = 0; mi < 4; ++mi) {
#pragma unroll
    for (int ni = 0; ni < 4; ++ni) {
      int n = n0 + wn * 64 + ni * 16 + (lane & 15);
      if (n < N) {
        float bv = bias[n];
#pragma unroll
        for (int q = 0; q < 4; ++q) {
          size_t m = row0 + (size_t)(wm * 64 + mi * 16 + (lane >> 4) * 4 + q);
          uint32_t b = (uint32_t)(m / NTOK);
          C[m * (size_t)N + n] = (acc[mi][ni][q] + bv) * msk[(size_t)b * N + n];
        }
      }
    }
  }
}

// ---------------------------------------------------------------------------
extern "C" void kernel_launch(void* const* d_in, const int* in_sizes, int n_in,
                              void* d_out, int out_size, void* d_ws, size_t ws_size,
                              hipStream_t stream)
{
  (void)in_sizes; (void)n_in; (void)out_size; (void)ws_size;
  const float* x = (const float*)d_in[0];
  const float *sg[4], *sb[4], *sW[4], *sbias[4], *pW1[4], *pb1[4], *pW2[4], *pb2[4];
  for (int s = 0; s < 4; ++s) {
    int base = 1 + s * 8;
    sg[s]    = (const float*)d_in[base + 0];
    sb[s]    = (const float*)d_in[base + 1];
    sW[s]    = (const float*)d_in[base + 2];
    sbias[s] = (const float*)d_in[base + 3];
    pW1[s]   = (const float*)d_in[base + 4];
    pb1[s]   = (const float*)d_in[base + 5];
    pW2[s]   = (const float*)d_in[base + 6];
    pb2[s]   = (const float*)d_in[base + 7];
  }

  // workspace layout (bytes, all 16-aligned):
  char* ws = (char*)d_ws;
  ushort* a_hi = (ushort*)(ws);                 // 77,070,336  (M*384 bf16)
  ushort* a_lo = (ushort*)(ws + 77070336);      // 38,535,168  (M*192 bf16)
  float*  part = (float*) (ws + 115605504);     //  3,145,728  (transposed [b][c][64])
  float*  mk   = (float*) (ws + 118751232);     //     98,304
  ushort* w_hi = (ushort*)(ws + 118849536);     //    811,008
  ushort* w_lo = (ushort*)(ws + 119660544);     //    811,008
  float*  st_g = (float*) (ws + 120471552);     //     98,304  -> end 120,569,856

  const int woff[4] = { 0, 12288, 36864, 110592 };

  // z1..z3 aliased into d_out (all dead before stage-4 GEMM overwrites):
  float* out = (float*)d_out;
  float* z3 = out;              // M*384
  float* z2 = out + 38535168;   // M*192
  float* z1 = out + 57802752;   // M*96

  convW_all_k<<<(405504 + 255) / 256, 256, 0, stream>>>(
      sW[0], sW[1], sW[2], sW[3], w_hi, w_lo);

  // ---- stage 1: K=96 -> N=96 (Npad=128), k = 86
  ln_colsum_k<96, true><<<512, 256, 0, stream>>>(x, sg[0], sb[0], a_hi, a_lo, part);
  st_k<96, 96, 1, 192><<<dim3(32, 1), 192, 0, stream>>>(part, sW[0], sbias[0], st_g);
  hscrank_k<96><<<32, 1024, 0, stream>>>(st_g, pW1[0], pb1[0], pW2[0], pb2[0], mk, 86);
  gemm_mfma_k<96, 3><<<dim3(784, 1), 256, 0, stream>>>(
      a_hi, a_hi, a_lo, w_hi + woff[0], w_lo + woff[0], w_hi + woff[0],
      sbias[0], mk, z1, 96);

  // ---- stage 2: K=96 -> N=192 (Npad=256), k = 134
  ln_colsum_k<96, true><<<512, 256, 0, stream>>>(z1, sg[1], sb[1], a_hi, a_lo, part);
  st_k<96, 192, 1, 384><<<dim3(32, 1), 384, 0, stream>>>(part, sW[1], sbias[1], st_g);
  hscrank_k<192><<<32, 1024, 0, stream>>>(st_g, pW1[1], pb1[1], pW2[1], pb2[1], mk, 134);
  gemm_mfma_k<96, 3><<<dim3(784, 2), 256, 0, stream>>>(
      a_hi, a_hi, a_lo, w_hi + woff[1], w_lo + woff[1], w_hi + woff[1],
      sbias[1], mk, z2, 192);

  // ---- stage 3: K=192 -> N=384, k = 192
  ln_colsum_k<192, true><<<512, 256, 0, stream>>>(z2, sg[2], sb[2], a_hi, a_lo, part);
  st_k<192, 384, 2, 384><<<dim3(32, 2), 384, 0, stream>>>(part, sW[2], sbias[2], st_g);
  hscrank_k<384><<<32, 1024, 0, stream>>>(st_g, pW1[2], pb1[2], pW2[2], pb2[2], mk, 192);
  gemm_mfma_k<192, 3><<<dim3(784, 3), 256, 0, stream>>>(
      a_hi, a_hi, a_lo, w_hi + woff[2], w_lo + woff[2], w_hi + woff[2],
      sbias[2], mk, z3, 384);

  // ---- stage 4: K=384 -> N=768, k = 230 (plain bf16; output-tolerance path)
  ln_colsum_k<384, false><<<512, 256, 0, stream>>>(z3, sg[3], sb[3], a_hi, a_hi, part);
  st_k<384, 768, 4, 384><<<dim3(32, 4), 384, 0, stream>>>(part, sW[3], sbias[3], st_g);
  hscrank_k<768><<<32, 1024, 0, stream>>>(st_g, pW1[3], pb1[3], pW2[3], pb2[3], mk, 230);
  gemm_mfma_k<384, 1><<<dim3(784, 6), 256, 0, stream>>>(
      a_hi, a_hi, a_hi, w_hi + woff[3], w_hi + woff[3], w_hi + woff[3],
      sbias[3], mk, out, 768);
}

// Round 5
// 620.002 us; speedup vs baseline: 2.8191x; 1.0794x over previous
//
#include <hip/hip_runtime.h>
#include <hip/hip_bf16.h>
#include <stdint.h>

#define NTOK 3136
#define MTOT 100352
#define RPW  14          // rows per LN wave
#define WPB  224         // LN waves per batch (NTOK/RPW)

typedef __attribute__((ext_vector_type(8))) short bf16x8;
typedef __attribute__((ext_vector_type(4))) float f32x4;
typedef __attribute__((ext_vector_type(2))) float f32x2;

static __device__ __forceinline__ ushort f2bf(float x) {
  union { float f; uint32_t u; } c; c.f = x;
  uint32_t r = (c.u + 0x7FFFu + ((c.u >> 16) & 1u)) >> 16;   // RNE
  return (ushort)r;
}
static __device__ __forceinline__ float bf2f(ushort h) {
  union { uint32_t u; float f; } c; c.u = ((uint32_t)h) << 16;
  return c.f;
}

// ---------------------------------------------------------------------------
// LayerNorm + fp32 column partial sums. Lanes own channel PAIRS (float2 in,
// packed-uint bf16-pair out). One wave per RPW=14 rows -> 7168 waves (28/CU).
// part layout: [b][c][WPB] so the reducer reads contiguous float4s.
// ---------------------------------------------------------------------------
template<int DIN, bool WLO>
__global__ __launch_bounds__(256)
void ln_colsum_k(const float* __restrict__ in, const float* __restrict__ gma,
                 const float* __restrict__ bta, ushort* __restrict__ oh,
                 ushort* __restrict__ ol, float* __restrict__ part)
{
  constexpr int P2 = DIN / 2;
  constexpr int T2 = (P2 + 63) / 64;
  const int wid  = (blockIdx.x * 256 + threadIdx.x) >> 6;
  const int lane = threadIdx.x & 63;
  const int b = wid / WPB;
  const int w = wid - b * WPB;

  f32x2 gv[T2], bv[T2], acc[T2];
#pragma unroll
  for (int t = 0; t < T2; ++t) {
    int c2 = lane + 64 * t;
    if (c2 < P2) {
      gv[t] = *(const f32x2*)(gma + 2 * c2);
      bv[t] = *(const f32x2*)(bta + 2 * c2);
    } else { gv[t] = {0.f, 0.f}; bv[t] = {0.f, 0.f}; }
    acc[t] = {0.f, 0.f};
  }

  const size_t rbase = ((size_t)b * NTOK + (size_t)w * RPW) * DIN;
  const float* ip = in + rbase;
  ushort* oph = oh + rbase;
  ushort* opl = ol + rbase;

  for (int j = 0; j < RPW; ++j) {
    f32x2 v[T2];
    float s = 0.f, sq = 0.f;
#pragma unroll
    for (int t = 0; t < T2; ++t) {
      int c2 = lane + 64 * t;
      f32x2 xv = {0.f, 0.f};
      if (c2 < P2) xv = *(const f32x2*)(ip + (size_t)j * DIN + 2 * c2);
      v[t] = xv;
      s  += xv[0] + xv[1];
      sq += xv[0] * xv[0] + xv[1] * xv[1];
    }
#pragma unroll
    for (int off = 1; off < 64; off <<= 1) {
      s  += __shfl_xor(s, off);
      sq += __shfl_xor(sq, off);
    }
    float m   = s / (float)DIN;
    float var = sq / (float)DIN - m * m;
    float r   = 1.f / sqrtf(var + 1e-5f);
#pragma unroll
    for (int t = 0; t < T2; ++t) {
      int c2 = lane + 64 * t;
      if (c2 < P2) {
        float xn0 = (v[t][0] - m) * r * gv[t][0] + bv[t][0];
        float xn1 = (v[t][1] - m) * r * gv[t][1] + bv[t][1];
        ushort h0 = f2bf(xn0), h1 = f2bf(xn1);
        ((uint32_t*)(oph + (size_t)j * DIN))[c2] =
            (uint32_t)h0 | ((uint32_t)h1 << 16);
        if (WLO) {
          ushort l0 = f2bf(xn0 - bf2f(h0)), l1 = f2bf(xn1 - bf2f(h1));
          ((uint32_t*)(opl + (size_t)j * DIN))[c2] =
              (uint32_t)l0 | ((uint32_t)l1 << 16);
        }
        acc[t][0] += xn0;
        acc[t][1] += xn1;
      }
    }
  }
#pragma unroll
  for (int t = 0; t < T2; ++t) {
    int c2 = lane + 64 * t;
    if (c2 < P2) {
      int c = 2 * c2;
      part[((size_t)b * DIN + c) * WPB + w]     = acc[t][0];
      part[((size_t)b * DIN + c + 1) * WPB + w] = acc[t][1];
    }
  }
}

// ---------------------------------------------------------------------------
// st_k: per (batch, col-chunk): xm = mean_tokens (from [b][c][WPB] part),
// st[chunk cols] = xm @ W + bias -> global. 8 k-slices x float4-cols.
// ---------------------------------------------------------------------------
template<int DIN, int DOUT, int CHUNKS, int BLK>
__global__ __launch_bounds__(BLK)
void st_k(const float* __restrict__ part, const float* __restrict__ Wt,
          const float* __restrict__ bias, float* __restrict__ st_g)
{
  constexpr int C4 = DOUT / 4 / CHUNKS;   // float4 cols per chunk
  constexpr int CW = C4 * 4;
  constexpr int SL = 8;
  constexpr int RPS = DIN / SL;
  static_assert(BLK == C4 * SL, "block size");
  constexpr int CG = BLK / 4;             // col-groups in phase A
  static_assert(DIN % CG == 0, "phase A tiling");
  constexpr int QW = WPB / 4;             // 56 floats = 14 f32x4 per quarter

  __shared__ float xm[DIN];
  __shared__ float redA[4][DIN];
  __shared__ float redB[SL][CW];

  const int b = blockIdx.x, ch = blockIdx.y, tid = threadIdx.x;

  // phase A: xm (4 threads per column, 14 independent float4 each)
  {
    const int cg = tid >> 2, wq = tid & 3;
#pragma unroll
    for (int i = 0; i < DIN / CG; ++i) {
      int c = cg + i * CG;
      const float* p = part + ((size_t)b * DIN + c) * WPB + wq * QW;
      f32x4 a = {0.f, 0.f, 0.f, 0.f};
#pragma unroll
      for (int u = 0; u < QW / 4; ++u) {
        f32x4 t0 = *(const f32x4*)(p + u * 4);
        a[0] += t0[0]; a[1] += t0[1]; a[2] += t0[2]; a[3] += t0[3];
      }
      redA[wq][c] = (a[0] + a[1]) + (a[2] + a[3]);
    }
  }
  __syncthreads();
  for (int c = tid; c < DIN; c += BLK)
    xm[c] = ((redA[0][c]+redA[1][c]) + (redA[2][c]+redA[3][c])) * (1.f/(float)NTOK);
  __syncthreads();

  // phase B: st chunk = xm @ W + bias
  {
    const int j4 = tid % C4, sl = tid / C4;
    const float* wp = Wt + (size_t)(sl * RPS) * DOUT + ch * CW + j4 * 4;
    f32x4 acc = {0.f, 0.f, 0.f, 0.f};
#pragma unroll
    for (int r = 0; r < RPS; ++r) {
      f32x4 wv = *(const f32x4*)(wp + (size_t)r * DOUT);
      float xv = xm[sl * RPS + r];
      acc[0] = fmaf(xv, wv[0], acc[0]);
      acc[1] = fmaf(xv, wv[1], acc[1]);
      acc[2] = fmaf(xv, wv[2], acc[2]);
      acc[3] = fmaf(xv, wv[3], acc[3]);
    }
    *(f32x4*)&redB[sl][j4 * 4] = acc;
  }
  __syncthreads();
  if (tid < CW) {
    int c = ch * CW + tid;
    float t0 = (redB[0][tid]+redB[1][tid]) + (redB[2][tid]+redB[3][tid]);
    float t1 = (redB[4][tid]+redB[5][tid]) + (redB[6][tid]+redB[7][tid]);
    st_g[(size_t)b * DOUT + c] = bias[c] + t0 + t1;
  }
}

// ---------------------------------------------------------------------------
// hscrank_k: per batch: h = relu(st@W1+b1), sc = h@W2+b2, stable rank -> mask.
// ---------------------------------------------------------------------------
template<int DOUT>
__global__ __launch_bounds__(1024)
void hscrank_k(const float* __restrict__ st_g,
               const float* __restrict__ W1, const float* __restrict__ b1,
               const float* __restrict__ W2, const float* __restrict__ b2,
               float* __restrict__ mask, int k)
{
  constexpr int DH  = DOUT / 4;
  constexpr int DH4 = DH / 4;
  constexpr int NSLC = (1024 / DH4 < 64) ? 1024 / DH4 : 64;
  constexpr int RPSC = (DOUT + NSLC - 1) / NSLC;
  constexpr int C4  = DOUT / 4;
  constexpr int NSLD = (1024 / C4 < 64) ? 1024 / C4 : 64;
  constexpr int RPSD = (DH + NSLD - 1) / NSLD;

  __shared__ float st[DOUT];
  __shared__ float h[DH];
  __shared__ float sc[DOUT];
  __shared__ float red[4096];

  const int b = blockIdx.x, tid = threadIdx.x;

  for (int c = tid; c < DOUT; c += 1024) st[c] = st_g[(size_t)b * DOUT + c];
  __syncthreads();

  {
    const int j4 = tid % DH4, sl = tid / DH4;
    if (sl < NSLC) {
      f32x4 acc = {0.f, 0.f, 0.f, 0.f};
#pragma unroll
      for (int rr = 0; rr < RPSC; ++rr) {
        int r = sl * RPSC + rr;
        if (r < DOUT) {
          f32x4 wv = *(const f32x4*)(W1 + (size_t)r * DH + j4 * 4);
          float sv = st[r];
          acc[0] = fmaf(sv, wv[0], acc[0]);
          acc[1] = fmaf(sv, wv[1], acc[1]);
          acc[2] = fmaf(sv, wv[2], acc[2]);
          acc[3] = fmaf(sv, wv[3], acc[3]);
        }
      }
      *(f32x4*)&red[(size_t)sl * DH + j4 * 4] = acc;
    }
  }
  __syncthreads();
  if (tid < DH) {
    float a = 0.f;
#pragma unroll 4
    for (int sl = 0; sl < NSLC; ++sl) a += red[(size_t)sl * DH + tid];
    h[tid] = fmaxf(b1[tid] + a, 0.f);
  }
  __syncthreads();

  {
    const int c4 = tid % C4, sl = tid / C4;
    if (sl < NSLD) {
      f32x4 acc = {0.f, 0.f, 0.f, 0.f};
#pragma unroll
      for (int rr = 0; rr < RPSD; ++rr) {
        int r = sl * RPSD + rr;
        if (r < DH) {
          f32x4 wv = *(const f32x4*)(W2 + (size_t)r * DOUT + c4 * 4);
          float hv = h[r];
          acc[0] = fmaf(hv, wv[0], acc[0]);
          acc[1] = fmaf(hv, wv[1], acc[1]);
          acc[2] = fmaf(hv, wv[2], acc[2]);
          acc[3] = fmaf(hv, wv[3], acc[3]);
        }
      }
      *(f32x4*)&red[(size_t)sl * DOUT + c4 * 4] = acc;
    }
  }
  __syncthreads();
  for (int c = tid; c < DOUT; c += 1024) {
    float a = 0.f;
#pragma unroll 4
    for (int sl = 0; sl < NSLD; ++sl) a += red[(size_t)sl * DOUT + c];
    sc[c] = b2[c] + a;
  }
  __syncthreads();

  for (int c = tid; c < DOUT; c += 1024) {
    float v = sc[c];
    int rank = 0;
#pragma unroll 8
    for (int j = 0; j < DOUT; ++j) {
      float u = sc[j];
      rank += (u > v) || (u == v && j < c);
    }
    mask[(size_t)b * DOUT + c] = (rank < k) ? 1.f : 0.f;
  }
}

// ---------------------------------------------------------------------------
// All 4 stages' W [K][N] fp32 -> hi/lo bf16 [Npad][K], hoisted to the start.
// ---------------------------------------------------------------------------
__global__ __launch_bounds__(256)
void convW_all_k(const float* __restrict__ W0, const float* __restrict__ W1,
                 const float* __restrict__ W2, const float* __restrict__ W3,
                 ushort* __restrict__ hi, ushort* __restrict__ lo)
{
  const int Kd[4]   = { 96, 96, 192, 384 };
  const int Nd[4]   = { 96, 192, 384, 768 };
  const int off[5]  = { 0, 12288, 36864, 110592, 405504 };
  const float* Wp[4] = { W0, W1, W2, W3 };

  int idx = blockIdx.x * 256 + threadIdx.x;
  if (idx >= 405504) return;
  int s = (idx >= off[1]) + (idx >= off[2]) + (idx >= off[3]);
  int local = idx - off[s];
  int K = Kd[s], N = Nd[s];
  int n = local / K, kk = local - n * K;
  float v = (n < N) ? Wp[s][(size_t)kk * N + n] : 0.f;
  ushort h = f2bf(v);
  hi[idx] = h;
  lo[idx] = f2bf(v - bf2f(h));
}

// ---------------------------------------------------------------------------
// MFMA GEMM: 128x128 tile, BK=32, 4 waves, source-pre-swizzled linear LDS +
// global_load_lds(16B), double-buffered. 1-D grid with n-inner + bijective
// XCD chunking so each XCD owns a contiguous m-band (A fetched once per L2).
// ---------------------------------------------------------------------------
#define ASYNC16(GP, LP) __builtin_amdgcn_global_load_lds( \
    (const __attribute__((address_space(1))) void*)(GP),  \
    (__attribute__((address_space(3))) void*)(LP), 16, 0, 0)

template<int K, int NSEG>
__global__ __launch_bounds__(256)
void gemm_mfma_k(const ushort* __restrict__ a0, const ushort* __restrict__ a1,
                 const ushort* __restrict__ a2,
                 const ushort* __restrict__ b0, const ushort* __restrict__ b1,
                 const ushort* __restrict__ b2,
                 const float* __restrict__ bias, const float* __restrict__ msk,
                 float* __restrict__ C, int N)
{
  constexpr int KSTEPS = K / 32;
  constexpr int NT = NSEG * KSTEPS;
  __shared__ __align__(16) ushort ldsA[2][128 * 32];
  __shared__ __align__(16) ushort ldsB[2][128 * 32];

  const int tid  = threadIdx.x;
  const int lane = tid & 63;
  const int wid  = tid >> 6;
  const int wm = wid >> 1, wn = wid & 1;

  // XCD-chunked bijective remap (gridDim.x % 8 == 0), n-tile innermost.
  const int NBN = (N + 127) >> 7;
  const int q8  = gridDim.x >> 3;
  const int bid = blockIdx.x;
  const int wg  = (bid & 7) * q8 + (bid >> 3);
  const int mt  = wg / NBN;
  const int nt  = wg - mt * NBN;
  const size_t row0 = (size_t)mt * 128;
  const int n0 = nt * 128;

  const ushort* Aseg[3] = { a0, a1, a2 };
  const ushort* Bseg[3] = { b0, b1, b2 };

  f32x4 acc[4][4];
#pragma unroll
  for (int i = 0; i < 4; ++i)
#pragma unroll
    for (int j = 0; j < 4; ++j) acc[i][j] = { 0.f, 0.f, 0.f, 0.f };

  const int c_row  = tid >> 2;
  const int c_phys = tid & 3;

#define STAGE(BUF, T)                                                          \
  {                                                                            \
    const int seg_ = (T) / KSTEPS;                                             \
    const int k0_  = ((T) % KSTEPS) * 32;                                      \
    const ushort* ap_ = Aseg[seg_];                                            \
    const ushort* bp_ = Bseg[seg_];                                            \
    _Pragma("unroll")                                                          \
    for (int r_ = 0; r_ < 2; ++r_) {                                           \
      int row_  = c_row + r_ * 64;                                             \
      int slot_ = c_phys ^ ((row_ >> 1) & 3);                                  \
      ASYNC16(ap_ + (row0 + row_) * (size_t)K + (k0_ + slot_ * 8),             \
              &ldsA[BUF][(row_ * 4 + c_phys) * 8]);                            \
      ASYNC16(bp_ + (size_t)(n0 + row_) * K + (k0_ + slot_ * 8),               \
              &ldsB[BUF][(row_ * 4 + c_phys) * 8]);                            \
    }                                                                          \
  }

  STAGE(0, 0);
#pragma unroll
  for (int t = 0; t < NT; ++t) {
    __syncthreads();
    if (t + 1 < NT) STAGE((t + 1) & 1, t + 1);
    const int buf = t & 1;
    const int slot = lane >> 4;
    const int r16  = lane & 15;
    bf16x8 af[4], bfr[4];
#pragma unroll
    for (int mi = 0; mi < 4; ++mi) {
      int r = wm * 64 + mi * 16 + r16;
      af[mi] = *(const bf16x8*)&ldsA[buf][(r * 4 + (slot ^ ((r >> 1) & 3))) * 8];
    }
#pragma unroll
    for (int ni = 0; ni < 4; ++ni) {
      int r = wn * 64 + ni * 16 + r16;
      bfr[ni] = *(const bf16x8*)&ldsB[buf][(r * 4 + (slot ^ ((r >> 1) & 3))) * 8];
    }
#pragma unroll
    for (int mi = 0; mi < 4; ++mi)
#pragma unroll
      for (int ni = 0; ni < 4; ++ni)
        acc[mi][ni] = __builtin_amdgcn_mfma_f32_16x16x32_bf16(af[mi], bfr[ni],
                                                              acc[mi][ni], 0, 0, 0);
  }

#pragma unroll
  for (int mi = 0; mi < 4; ++mi) {
#pragma unroll
    for (int ni = 0; ni < 4; ++ni) {
      int n = n0 + wn * 64 + ni * 16 + (lane & 15);
      if (n < N) {
        float bv = bias[n];
#pragma unroll
        for (int q = 0; q < 4; ++q) {
          size_t m = row0 + (size_t)(wm * 64 + mi * 16 + (lane >> 4) * 4 + q);
          uint32_t b = (uint32_t)(m / NTOK);
          C[m * (size_t)N + n] = (acc[mi][ni][q] + bv) * msk[(size_t)b * N + n];
        }
      }
    }
  }
}

// ---------------------------------------------------------------------------
extern "C" void kernel_launch(void* const* d_in, const int* in_sizes, int n_in,
                              void* d_out, int out_size, void* d_ws, size_t ws_size,
                              hipStream_t stream)
{
  (void)in_sizes; (void)n_in; (void)out_size; (void)ws_size;
  const float* x = (const float*)d_in[0];
  const float *sg[4], *sb[4], *sW[4], *sbias[4], *pW1[4], *pb1[4], *pW2[4], *pb2[4];
  for (int s = 0; s < 4; ++s) {
    int base = 1 + s * 8;
    sg[s]    = (const float*)d_in[base + 0];
    sb[s]    = (const float*)d_in[base + 1];
    sW[s]    = (const float*)d_in[base + 2];
    sbias[s] = (const float*)d_in[base + 3];
    pW1[s]   = (const float*)d_in[base + 4];
    pb1[s]   = (const float*)d_in[base + 5];
    pW2[s]   = (const float*)d_in[base + 6];
    pb2[s]   = (const float*)d_in[base + 7];
  }

  // workspace layout (bytes, all 16-aligned):
  char* ws = (char*)d_ws;
  ushort* a_hi = (ushort*)(ws);                 // 77,070,336  (M*384 bf16)
  ushort* a_lo = (ushort*)(ws + 77070336);      // 38,535,168  (M*192 bf16)
  float*  part = (float*) (ws + 115605504);     // 11,010,048  ([b][c][224])
  float*  mk   = (float*) (ws + 126615552);     //     98,304
  ushort* w_hi = (ushort*)(ws + 126713856);     //    811,008
  ushort* w_lo = (ushort*)(ws + 127524864);     //    811,008
  float*  st_g = (float*) (ws + 128335872);     //     98,304  -> end 128,434,176

  const int woff[4] = { 0, 12288, 36864, 110592 };

  // z1..z3 aliased into d_out (all dead before stage-4 GEMM overwrites):
  float* out = (float*)d_out;
  float* z3 = out;              // M*384
  float* z2 = out + 38535168;   // M*192
  float* z1 = out + 57802752;   // M*96

  convW_all_k<<<(405504 + 255) / 256, 256, 0, stream>>>(
      sW[0], sW[1], sW[2], sW[3], w_hi, w_lo);

  // LN grid: 32 batches * WPB waves / 4 waves-per-block = 1792 blocks
  const int LNG = 32 * WPB / 4;

  // ---- stage 1: K=96 -> N=96 (Npad=128), k = 86
  ln_colsum_k<96, true><<<LNG, 256, 0, stream>>>(x, sg[0], sb[0], a_hi, a_lo, part);
  st_k<96, 96, 1, 192><<<dim3(32, 1), 192, 0, stream>>>(part, sW[0], sbias[0], st_g);
  hscrank_k<96><<<32, 1024, 0, stream>>>(st_g, pW1[0], pb1[0], pW2[0], pb2[0], mk, 86);
  gemm_mfma_k<96, 3><<<784, 256, 0, stream>>>(
      a_hi, a_hi, a_lo, w_hi + woff[0], w_lo + woff[0], w_hi + woff[0],
      sbias[0], mk, z1, 96);

  // ---- stage 2: K=96 -> N=192 (Npad=256), k = 134
  ln_colsum_k<96, true><<<LNG, 256, 0, stream>>>(z1, sg[1], sb[1], a_hi, a_lo, part);
  st_k<96, 192, 1, 384><<<dim3(32, 1), 384, 0, stream>>>(part, sW[1], sbias[1], st_g);
  hscrank_k<192><<<32, 1024, 0, stream>>>(st_g, pW1[1], pb1[1], pW2[1], pb2[1], mk, 134);
  gemm_mfma_k<96, 3><<<784 * 2, 256, 0, stream>>>(
      a_hi, a_hi, a_lo, w_hi + woff[1], w_lo + woff[1], w_hi + woff[1],
      sbias[1], mk, z2, 192);

  // ---- stage 3: K=192 -> N=384, k = 192
  ln_colsum_k<192, true><<<LNG, 256, 0, stream>>>(z2, sg[2], sb[2], a_hi, a_lo, part);
  st_k<192, 384, 2, 384><<<dim3(32, 2), 384, 0, stream>>>(part, sW[2], sbias[2], st_g);
  hscrank_k<384><<<32, 1024, 0, stream>>>(st_g, pW1[2], pb1[2], pW2[2], pb2[2], mk, 192);
  gemm_mfma_k<192, 3><<<784 * 3, 256, 0, stream>>>(
      a_hi, a_hi, a_lo, w_hi + woff[2], w_lo + woff[2], w_hi + woff[2],
      sbias[2], mk, z3, 384);

  // ---- stage 4: K=384 -> N=768, k = 230 (plain bf16; output-tolerance path)
  ln_colsum_k<384, false><<<LNG, 256, 0, stream>>>(z3, sg[3], sb[3], a_hi, a_hi, part);
  st_k<384, 768, 4, 384><<<dim3(32, 4), 384, 0, stream>>>(part, sW[3], sbias[3], st_g);
  hscrank_k<768><<<32, 1024, 0, stream>>>(st_g, pW1[3], pb1[3], pW2[3], pb2[3], mk, 230);
  gemm_mfma_k<384, 1><<<784 * 6, 256, 0, stream>>>(
      a_hi, a_hi, a_hi, w_hi + woff[3], w_hi + woff[3], w_hi + woff[3],
      sbias[3], mk, out, 768);
}

// Round 6
// 583.006 us; speedup vs baseline: 2.9980x; 1.0635x over previous
//
#include <hip/hip_runtime.h>
#include <hip/hip_bf16.h>
#include <stdint.h>

#define NTOK 3136
#define MTOT 100352
#define RPW  14          // rows per LN wave
#define WPB  224         // LN waves per batch (NTOK/RPW)

typedef __attribute__((ext_vector_type(8))) short bf16x8;
typedef __attribute__((ext_vector_type(4))) float f32x4;
typedef __attribute__((ext_vector_type(2))) float f32x2;

static __device__ __forceinline__ ushort f2bf(float x) {
  union { float f; uint32_t u; } c; c.f = x;
  uint32_t r = (c.u + 0x7FFFu + ((c.u >> 16) & 1u)) >> 16;   // RNE
  return (ushort)r;
}
static __device__ __forceinline__ float bf2f(ushort h) {
  union { uint32_t u; float f; } c; c.u = ((uint32_t)h) << 16;
  return c.f;
}

// ---------------------------------------------------------------------------
// LayerNorm + fp32 column partial sums. Lanes own channel PAIRS (float2 in,
// packed-uint bf16-pair out). One wave per RPW=14 rows -> 7168 waves (28/CU).
// part layout: [b][c][WPB] so the reducer reads contiguous float4s.
// ---------------------------------------------------------------------------
template<int DIN, bool WLO>
__global__ __launch_bounds__(256)
void ln_colsum_k(const float* __restrict__ in, const float* __restrict__ gma,
                 const float* __restrict__ bta, ushort* __restrict__ oh,
                 ushort* __restrict__ ol, float* __restrict__ part)
{
  constexpr int P2 = DIN / 2;
  constexpr int T2 = (P2 + 63) / 64;
  const int wid  = (blockIdx.x * 256 + threadIdx.x) >> 6;
  const int lane = threadIdx.x & 63;
  const int b = wid / WPB;
  const int w = wid - b * WPB;

  f32x2 gv[T2], bv[T2], acc[T2];
#pragma unroll
  for (int t = 0; t < T2; ++t) {
    int c2 = lane + 64 * t;
    if (c2 < P2) {
      gv[t] = *(const f32x2*)(gma + 2 * c2);
      bv[t] = *(const f32x2*)(bta + 2 * c2);
    } else { gv[t] = {0.f, 0.f}; bv[t] = {0.f, 0.f}; }
    acc[t] = {0.f, 0.f};
  }

  const size_t rbase = ((size_t)b * NTOK + (size_t)w * RPW) * DIN;
  const float* ip = in + rbase;
  ushort* oph = oh + rbase;
  ushort* opl = ol + rbase;

  for (int j = 0; j < RPW; ++j) {
    f32x2 v[T2];
    float s = 0.f, sq = 0.f;
#pragma unroll
    for (int t = 0; t < T2; ++t) {
      int c2 = lane + 64 * t;
      f32x2 xv = {0.f, 0.f};
      if (c2 < P2) xv = *(const f32x2*)(ip + (size_t)j * DIN + 2 * c2);
      v[t] = xv;
      s  += xv[0] + xv[1];
      sq += xv[0] * xv[0] + xv[1] * xv[1];
    }
#pragma unroll
    for (int off = 1; off < 64; off <<= 1) {
      s  += __shfl_xor(s, off);
      sq += __shfl_xor(sq, off);
    }
    float m   = s / (float)DIN;
    float var = sq / (float)DIN - m * m;
    float r   = 1.f / sqrtf(var + 1e-5f);
#pragma unroll
    for (int t = 0; t < T2; ++t) {
      int c2 = lane + 64 * t;
      if (c2 < P2) {
        float xn0 = (v[t][0] - m) * r * gv[t][0] + bv[t][0];
        float xn1 = (v[t][1] - m) * r * gv[t][1] + bv[t][1];
        ushort h0 = f2bf(xn0), h1 = f2bf(xn1);
        ((uint32_t*)(oph + (size_t)j * DIN))[c2] =
            (uint32_t)h0 | ((uint32_t)h1 << 16);
        if (WLO) {
          ushort l0 = f2bf(xn0 - bf2f(h0)), l1 = f2bf(xn1 - bf2f(h1));
          ((uint32_t*)(opl + (size_t)j * DIN))[c2] =
              (uint32_t)l0 | ((uint32_t)l1 << 16);
        }
        acc[t][0] += xn0;
        acc[t][1] += xn1;
      }
    }
  }
#pragma unroll
  for (int t = 0; t < T2; ++t) {
    int c2 = lane + 64 * t;
    if (c2 < P2) {
      int c = 2 * c2;
      part[((size_t)b * DIN + c) * WPB + w]     = acc[t][0];
      part[((size_t)b * DIN + c + 1) * WPB + w] = acc[t][1];
    }
  }
}

// ---------------------------------------------------------------------------
// st_k: per (batch, col-chunk): xm = mean_tokens (from [b][c][WPB] part),
// st[chunk cols] = xm @ W + bias -> global. 8 k-slices x float4-cols.
// ---------------------------------------------------------------------------
template<int DIN, int DOUT, int CHUNKS, int BLK>
__global__ __launch_bounds__(BLK)
void st_k(const float* __restrict__ part, const float* __restrict__ Wt,
          const float* __restrict__ bias, float* __restrict__ st_g)
{
  constexpr int C4 = DOUT / 4 / CHUNKS;   // float4 cols per chunk
  constexpr int CW = C4 * 4;
  constexpr int SL = 8;
  constexpr int RPS = DIN / SL;
  static_assert(BLK == C4 * SL, "block size");
  constexpr int CG = BLK / 4;             // col-groups in phase A
  static_assert(DIN % CG == 0, "phase A tiling");
  constexpr int QW = WPB / 4;             // 56 floats = 14 f32x4 per quarter

  __shared__ float xm[DIN];
  __shared__ float redA[4][DIN];
  __shared__ float redB[SL][CW];

  const int b = blockIdx.x, ch = blockIdx.y, tid = threadIdx.x;

  // phase A: xm (4 threads per column, 14 independent float4 each)
  {
    const int cg = tid >> 2, wq = tid & 3;
#pragma unroll
    for (int i = 0; i < DIN / CG; ++i) {
      int c = cg + i * CG;
      const float* p = part + ((size_t)b * DIN + c) * WPB + wq * QW;
      f32x4 a = {0.f, 0.f, 0.f, 0.f};
#pragma unroll
      for (int u = 0; u < QW / 4; ++u) {
        f32x4 t0 = *(const f32x4*)(p + u * 4);
        a[0] += t0[0]; a[1] += t0[1]; a[2] += t0[2]; a[3] += t0[3];
      }
      redA[wq][c] = (a[0] + a[1]) + (a[2] + a[3]);
    }
  }
  __syncthreads();
  for (int c = tid; c < DIN; c += BLK)
    xm[c] = ((redA[0][c]+redA[1][c]) + (redA[2][c]+redA[3][c])) * (1.f/(float)NTOK);
  __syncthreads();

  // phase B: st chunk = xm @ W + bias
  {
    const int j4 = tid % C4, sl = tid / C4;
    const float* wp = Wt + (size_t)(sl * RPS) * DOUT + ch * CW + j4 * 4;
    f32x4 acc = {0.f, 0.f, 0.f, 0.f};
#pragma unroll
    for (int r = 0; r < RPS; ++r) {
      f32x4 wv = *(const f32x4*)(wp + (size_t)r * DOUT);
      float xv = xm[sl * RPS + r];
      acc[0] = fmaf(xv, wv[0], acc[0]);
      acc[1] = fmaf(xv, wv[1], acc[1]);
      acc[2] = fmaf(xv, wv[2], acc[2]);
      acc[3] = fmaf(xv, wv[3], acc[3]);
    }
    *(f32x4*)&redB[sl][j4 * 4] = acc;
  }
  __syncthreads();
  if (tid < CW) {
    int c = ch * CW + tid;
    float t0 = (redB[0][tid]+redB[1][tid]) + (redB[2][tid]+redB[3][tid]);
    float t1 = (redB[4][tid]+redB[5][tid]) + (redB[6][tid]+redB[7][tid]);
    st_g[(size_t)b * DOUT + c] = bias[c] + t0 + t1;
  }
}

// ---------------------------------------------------------------------------
// hscrank_k: per batch: h = relu(st@W1+b1), sc = h@W2+b2, stable rank -> mask.
// ---------------------------------------------------------------------------
template<int DOUT>
__global__ __launch_bounds__(1024)
void hscrank_k(const float* __restrict__ st_g,
               const float* __restrict__ W1, const float* __restrict__ b1,
               const float* __restrict__ W2, const float* __restrict__ b2,
               float* __restrict__ mask, int k)
{
  constexpr int DH  = DOUT / 4;
  constexpr int DH4 = DH / 4;
  constexpr int NSLC = (1024 / DH4 < 64) ? 1024 / DH4 : 64;
  constexpr int RPSC = (DOUT + NSLC - 1) / NSLC;
  constexpr int C4  = DOUT / 4;
  constexpr int NSLD = (1024 / C4 < 64) ? 1024 / C4 : 64;
  constexpr int RPSD = (DH + NSLD - 1) / NSLD;

  __shared__ float st[DOUT];
  __shared__ float h[DH];
  __shared__ float sc[DOUT];
  __shared__ float red[4096];

  const int b = blockIdx.x, tid = threadIdx.x;

  for (int c = tid; c < DOUT; c += 1024) st[c] = st_g[(size_t)b * DOUT + c];
  __syncthreads();

  {
    const int j4 = tid % DH4, sl = tid / DH4;
    if (sl < NSLC) {
      f32x4 acc = {0.f, 0.f, 0.f, 0.f};
#pragma unroll
      for (int rr = 0; rr < RPSC; ++rr) {
        int r = sl * RPSC + rr;
        if (r < DOUT) {
          f32x4 wv = *(const f32x4*)(W1 + (size_t)r * DH + j4 * 4);
          float sv = st[r];
          acc[0] = fmaf(sv, wv[0], acc[0]);
          acc[1] = fmaf(sv, wv[1], acc[1]);
          acc[2] = fmaf(sv, wv[2], acc[2]);
          acc[3] = fmaf(sv, wv[3], acc[3]);
        }
      }
      *(f32x4*)&red[(size_t)sl * DH + j4 * 4] = acc;
    }
  }
  __syncthreads();
  if (tid < DH) {
    float a = 0.f;
#pragma unroll 4
    for (int sl = 0; sl < NSLC; ++sl) a += red[(size_t)sl * DH + tid];
    h[tid] = fmaxf(b1[tid] + a, 0.f);
  }
  __syncthreads();

  {
    const int c4 = tid % C4, sl = tid / C4;
    if (sl < NSLD) {
      f32x4 acc = {0.f, 0.f, 0.f, 0.f};
#pragma unroll
      for (int rr = 0; rr < RPSD; ++rr) {
        int r = sl * RPSD + rr;
        if (r < DH) {
          f32x4 wv = *(const f32x4*)(W2 + (size_t)r * DOUT + c4 * 4);
          float hv = h[r];
          acc[0] = fmaf(hv, wv[0], acc[0]);
          acc[1] = fmaf(hv, wv[1], acc[1]);
          acc[2] = fmaf(hv, wv[2], acc[2]);
          acc[3] = fmaf(hv, wv[3], acc[3]);
        }
      }
      *(f32x4*)&red[(size_t)sl * DOUT + c4 * 4] = acc;
    }
  }
  __syncthreads();
  for (int c = tid; c < DOUT; c += 1024) {
    float a = 0.f;
#pragma unroll 4
    for (int sl = 0; sl < NSLD; ++sl) a += red[(size_t)sl * DOUT + c];
    sc[c] = b2[c] + a;
  }
  __syncthreads();

  for (int c = tid; c < DOUT; c += 1024) {
    float v = sc[c];
    int rank = 0;
#pragma unroll 8
    for (int j = 0; j < DOUT; ++j) {
      float u = sc[j];
      rank += (u > v) || (u == v && j < c);
    }
    mask[(size_t)b * DOUT + c] = (rank < k) ? 1.f : 0.f;
  }
}

// ---------------------------------------------------------------------------
// All 4 stages' W [K][N] fp32 -> hi/lo bf16 [Npad][K], hoisted to the start.
// ---------------------------------------------------------------------------
__global__ __launch_bounds__(256)
void convW_all_k(const float* __restrict__ W0, const float* __restrict__ W1,
                 const float* __restrict__ W2, const float* __restrict__ W3,
                 ushort* __restrict__ hi, ushort* __restrict__ lo)
{
  const int Kd[4]   = { 96, 96, 192, 384 };
  const int Nd[4]   = { 96, 192, 384, 768 };
  const int off[5]  = { 0, 12288, 36864, 110592, 405504 };
  const float* Wp[4] = { W0, W1, W2, W3 };

  int idx = blockIdx.x * 256 + threadIdx.x;
  if (idx >= 405504) return;
  int s = (idx >= off[1]) + (idx >= off[2]) + (idx >= off[3]);
  int local = idx - off[s];
  int K = Kd[s], N = Nd[s];
  int n = local / K, kk = local - n * K;
  float v = (n < N) ? Wp[s][(size_t)kk * N + n] : 0.f;
  ushort h = f2bf(v);
  hi[idx] = h;
  lo[idx] = f2bf(v - bf2f(h));
}

// ---------------------------------------------------------------------------
// MFMA GEMM: 128x128 tile, BK=32, 4 waves, source-pre-swizzled linear LDS +
// global_load_lds(16B). TRIPLE-buffered with counted s_waitcnt vmcnt(4) and
// raw s_barrier (one barrier per K-step; loads stay in flight across it —
// prefetch distance 2 steps covers HBM latency). STAGE is issued AFTER the
// barrier: all waves have finished reading the buffer being overwritten.
// Epilogue: batch via boundary compare (no int div), mask/bias hoisted.
// ---------------------------------------------------------------------------
#define ASYNC16(GP, LP) __builtin_amdgcn_global_load_lds( \
    (const __attribute__((address_space(1))) void*)(GP),  \
    (__attribute__((address_space(3))) void*)(LP), 16, 0, 0)

template<int K, int NSEG>
__global__ __launch_bounds__(256)
void gemm_mfma_k(const ushort* __restrict__ a0, const ushort* __restrict__ a1,
                 const ushort* __restrict__ a2,
                 const ushort* __restrict__ b0, const ushort* __restrict__ b1,
                 const ushort* __restrict__ b2,
                 const float* __restrict__ bias, const float* __restrict__ msk,
                 float* __restrict__ C, int N)
{
  constexpr int KSTEPS = K / 32;
  constexpr int NT = NSEG * KSTEPS;
  __shared__ __align__(16) ushort ldsA[3][128 * 32];
  __shared__ __align__(16) ushort ldsB[3][128 * 32];

  const int tid  = threadIdx.x;
  const int lane = tid & 63;
  const int wid  = tid >> 6;
  const int wm = wid >> 1, wn = wid & 1;

  // XCD-chunked bijective remap (gridDim.x % 8 == 0), n-tile innermost.
  const int NBN = (N + 127) >> 7;
  const int q8  = gridDim.x >> 3;
  const int bid = blockIdx.x;
  const int wg  = (bid & 7) * q8 + (bid >> 3);
  const int mt  = wg / NBN;
  const int nt  = wg - mt * NBN;
  const size_t row0 = (size_t)mt * 128;
  const int n0 = nt * 128;

  const ushort* Aseg[3] = { a0, a1, a2 };
  const ushort* Bseg[3] = { b0, b1, b2 };

  f32x4 acc[4][4];
#pragma unroll
  for (int i = 0; i < 4; ++i)
#pragma unroll
    for (int j = 0; j < 4; ++j) acc[i][j] = { 0.f, 0.f, 0.f, 0.f };

  const int c_row  = tid >> 2;
  const int c_phys = tid & 3;

#define STAGE(BUF, T)                                                          \
  {                                                                            \
    const int seg_ = (T) / KSTEPS;                                             \
    const int k0_  = ((T) % KSTEPS) * 32;                                      \
    const ushort* ap_ = Aseg[seg_];                                            \
    const ushort* bp_ = Bseg[seg_];                                            \
    _Pragma("unroll")                                                          \
    for (int r_ = 0; r_ < 2; ++r_) {                                           \
      int row_  = c_row + r_ * 64;                                             \
      int slot_ = c_phys ^ ((row_ >> 1) & 3);                                  \
      ASYNC16(ap_ + (row0 + row_) * (size_t)K + (k0_ + slot_ * 8),             \
              &ldsA[BUF][(row_ * 4 + c_phys) * 8]);                            \
      ASYNC16(bp_ + (size_t)(n0 + row_) * K + (k0_ + slot_ * 8),               \
              &ldsB[BUF][(row_ * 4 + c_phys) * 8]);                            \
    }                                                                          \
  }

  STAGE(0, 0);
  STAGE(1, 1);
#pragma unroll
  for (int t = 0; t < NT; ++t) {
    // wait for buf t's 4 loads (the 4 loads of t+1 may stay in flight)
    if (t == NT - 1) { asm volatile("s_waitcnt vmcnt(0)" ::: "memory"); }
    else             { asm volatile("s_waitcnt vmcnt(4)" ::: "memory"); }
    __builtin_amdgcn_s_barrier();
    if (t + 2 < NT) STAGE((t + 2) % 3, t + 2);
    const int buf = t % 3;
    const int slot = lane >> 4;
    const int r16  = lane & 15;
    bf16x8 af[4], bfr[4];
#pragma unroll
    for (int mi = 0; mi < 4; ++mi) {
      int r = wm * 64 + mi * 16 + r16;
      af[mi] = *(const bf16x8*)&ldsA[buf][(r * 4 + (slot ^ ((r >> 1) & 3))) * 8];
    }
#pragma unroll
    for (int ni = 0; ni < 4; ++ni) {
      int r = wn * 64 + ni * 16 + r16;
      bfr[ni] = *(const bf16x8*)&ldsB[buf][(r * 4 + (slot ^ ((r >> 1) & 3))) * 8];
    }
#pragma unroll
    for (int mi = 0; mi < 4; ++mi)
#pragma unroll
      for (int ni = 0; ni < 4; ++ni)
        acc[mi][ni] = __builtin_amdgcn_mfma_f32_16x16x32_bf16(af[mi], bfr[ni],
                                                              acc[mi][ni], 0, 0, 0);
  }

  // epilogue: no divisions; mask/bias hoisted per output column
  const int b0i = (int)(row0 / NTOK);              // scalar, once
  const size_t rowB = (size_t)(b0i + 1) * NTOK;    // batch boundary row
  const bool straddle = (rowB < row0 + 128) && (b0i + 1 < 32);

#pragma unroll
  for (int ni = 0; ni < 4; ++ni) {
    int n = n0 + wn * 64 + ni * 16 + (lane & 15);
    if (n < N) {
      float bv  = bias[n];
      float mk0 = msk[(size_t)b0i * N + n];
      float mk1 = straddle ? msk[(size_t)(b0i + 1) * N + n] : mk0;
#pragma unroll
      for (int mi = 0; mi < 4; ++mi) {
#pragma unroll
        for (int q = 0; q < 4; ++q) {
          size_t m = row0 + (size_t)(wm * 64 + mi * 16 + (lane >> 4) * 4 + q);
          float mv = (m < rowB) ? mk0 : mk1;
          C[m * (size_t)N + n] = (acc[mi][ni][q] + bv) * mv;
        }
      }
    }
  }
}

// ---------------------------------------------------------------------------
extern "C" void kernel_launch(void* const* d_in, const int* in_sizes, int n_in,
                              void* d_out, int out_size, void* d_ws, size_t ws_size,
                              hipStream_t stream)
{
  (void)in_sizes; (void)n_in; (void)out_size; (void)ws_size;
  const float* x = (const float*)d_in[0];
  const float *sg[4], *sb[4], *sW[4], *sbias[4], *pW1[4], *pb1[4], *pW2[4], *pb2[4];
  for (int s = 0; s < 4; ++s) {
    int base = 1 + s * 8;
    sg[s]    = (const float*)d_in[base + 0];
    sb[s]    = (const float*)d_in[base + 1];
    sW[s]    = (const float*)d_in[base + 2];
    sbias[s] = (const float*)d_in[base + 3];
    pW1[s]   = (const float*)d_in[base + 4];
    pb1[s]   = (const float*)d_in[base + 5];
    pW2[s]   = (const float*)d_in[base + 6];
    pb2[s]   = (const float*)d_in[base + 7];
  }

  // workspace layout (bytes, all 16-aligned):
  char* ws = (char*)d_ws;
  ushort* a_hi = (ushort*)(ws);                 // 77,070,336  (M*384 bf16)
  ushort* a_lo = (ushort*)(ws + 77070336);      // 38,535,168  (M*192 bf16)
  float*  part = (float*) (ws + 115605504);     // 11,010,048  ([b][c][224])
  float*  mk   = (float*) (ws + 126615552);     //     98,304
  ushort* w_hi = (ushort*)(ws + 126713856);     //    811,008
  ushort* w_lo = (ushort*)(ws + 127524864);     //    811,008
  float*  st_g = (float*) (ws + 128335872);     //     98,304  -> end 128,434,176

  const int woff[4] = { 0, 12288, 36864, 110592 };

  // z1..z3 aliased into d_out (all dead before stage-4 GEMM overwrites):
  float* out = (float*)d_out;
  float* z3 = out;              // M*384
  float* z2 = out + 38535168;   // M*192
  float* z1 = out + 57802752;   // M*96

  convW_all_k<<<(405504 + 255) / 256, 256, 0, stream>>>(
      sW[0], sW[1], sW[2], sW[3], w_hi, w_lo);

  // LN grid: 32 batches * WPB waves / 4 waves-per-block = 1792 blocks
  const int LNG = 32 * WPB / 4;

  // ---- stage 1: K=96 -> N=96 (Npad=128), k = 86
  ln_colsum_k<96, true><<<LNG, 256, 0, stream>>>(x, sg[0], sb[0], a_hi, a_lo, part);
  st_k<96, 96, 1, 192><<<dim3(32, 1), 192, 0, stream>>>(part, sW[0], sbias[0], st_g);
  hscrank_k<96><<<32, 1024, 0, stream>>>(st_g, pW1[0], pb1[0], pW2[0], pb2[0], mk, 86);
  gemm_mfma_k<96, 3><<<784, 256, 0, stream>>>(
      a_hi, a_hi, a_lo, w_hi + woff[0], w_lo + woff[0], w_hi + woff[0],
      sbias[0], mk, z1, 96);

  // ---- stage 2: K=96 -> N=192 (Npad=256), k = 134
  ln_colsum_k<96, true><<<LNG, 256, 0, stream>>>(z1, sg[1], sb[1], a_hi, a_lo, part);
  st_k<96, 192, 1, 384><<<dim3(32, 1), 384, 0, stream>>>(part, sW[1], sbias[1], st_g);
  hscrank_k<192><<<32, 1024, 0, stream>>>(st_g, pW1[1], pb1[1], pW2[1], pb2[1], mk, 134);
  gemm_mfma_k<96, 3><<<784 * 2, 256, 0, stream>>>(
      a_hi, a_hi, a_lo, w_hi + woff[1], w_lo + woff[1], w_hi + woff[1],
      sbias[1], mk, z2, 192);

  // ---- stage 3: K=192 -> N=384, k = 192
  ln_colsum_k<192, true><<<LNG, 256, 0, stream>>>(z2, sg[2], sb[2], a_hi, a_lo, part);
  st_k<192, 384, 2, 384><<<dim3(32, 2), 384, 0, stream>>>(part, sW[2], sbias[2], st_g);
  hscrank_k<384><<<32, 1024, 0, stream>>>(st_g, pW1[2], pb1[2], pW2[2], pb2[2], mk, 192);
  gemm_mfma_k<192, 3><<<784 * 3, 256, 0, stream>>>(
      a_hi, a_hi, a_lo, w_hi + woff[2], w_lo + woff[2], w_hi + woff[2],
      sbias[2], mk, z3, 384);

  // ---- stage 4: K=384 -> N=768, k = 230 (plain bf16; output-tolerance path)
  ln_colsum_k<384, false><<<LNG, 256, 0, stream>>>(z3, sg[3], sb[3], a_hi, a_hi, part);
  st_k<384, 768, 4, 384><<<dim3(32, 4), 384, 0, stream>>>(part, sW[3], sbias[3], st_g);
  hscrank_k<768><<<32, 1024, 0, stream>>>(st_g, pW1[3], pb1[3], pW2[3], pb2[3], mk, 230);
  gemm_mfma_k<384, 1><<<784 * 6, 256, 0, stream>>>(
      a_hi, a_hi, a_hi, w_hi + woff[3], w_hi + woff[3], w_hi + woff[3],
      sbias[3], mk, out, 768);
}